// Round 1
// baseline (1580.463 us; speedup 1.0000x reference)
//
#include <hip/hip_runtime.h>
#include <math.h>

#define N_NODES 100000
#define N_EDGES 1600000
#define D_IN 64
#define D_HID 128

// ---------------- degree / norm ----------------

__global__ void k_init_deg(float* __restrict__ deg, int n) {
    int i = blockIdx.x * blockDim.x + threadIdx.x;
    if (i < n) deg[i] = 1.0f;  // self-loop contributes 1
}

__global__ void k_count(const int* __restrict__ col, float* __restrict__ deg, int e) {
    int i = blockIdx.x * blockDim.x + threadIdx.x;
    if (i < e) unsafeAtomicAdd(&deg[col[i]], 1.0f);
}

__global__ void k_dinv(float* __restrict__ deg, int n) {
    int i = blockIdx.x * blockDim.x + threadIdx.x;
    if (i < n) deg[i] = rsqrtf(deg[i]);  // deg >= 1 always (self-loops)
}

// ---------------- layer 1: y = dinv * (|x| @ W1); agg initialized to y (self-loop) ----

__global__ void k_xw(const float* __restrict__ x, const float* __restrict__ W1,
                     const float* __restrict__ dinv,
                     float* __restrict__ y, float* __restrict__ agg) {
    __shared__ float xs[D_IN];
    const int node = blockIdx.x;
    const int j = threadIdx.x;  // 0..127
    if (j < D_IN) xs[j] = fabsf(x[(size_t)node * D_IN + j]);
    __syncthreads();
    float acc = 0.0f;
#pragma unroll
    for (int k = 0; k < D_IN; ++k) acc = fmaf(xs[k], W1[k * D_HID + j], acc);
    const float v = dinv[node] * acc;
    y[(size_t)node * D_HID + j] = v;
    agg[(size_t)node * D_HID + j] = v;  // self-loop term
}

// ---------------- layer 1 scatter: agg[col] += y[row], one wave per edge ----------

__global__ void k_scatter(const int* __restrict__ row, const int* __restrict__ col,
                          const float* __restrict__ y, float* __restrict__ agg) {
    const int t = blockIdx.x * blockDim.x + threadIdx.x;
    const int e = t >> 6;   // one 64-lane wave per edge
    const int lane = t & 63;
    if (e >= N_EDGES) return;
    const int r = row[e];
    const int c = col[e];
    const float2 v = ((const float2*)(y + (size_t)r * D_HID))[lane];
    float* dst = agg + (size_t)c * D_HID + lane * 2;
    unsafeAtomicAdd(dst, v.x);
    unsafeAtomicAdd(dst + 1, v.y);
}

// ---------------- layer 1 finish fused with layer 2 pre-scale -----------------
// h = relu(dinv*agg + b1); z = dinv * (h . W2); agg2 init = z (self-loop)

__global__ void k_finish1(const float* __restrict__ agg, const float* __restrict__ dinv,
                          const float* __restrict__ b1, const float* __restrict__ W2,
                          float* __restrict__ z, float* __restrict__ agg2) {
    const int t = blockIdx.x * blockDim.x + threadIdx.x;
    const int node = t >> 6;  // one wave per node
    const int lane = t & 63;
    if (node >= N_NODES) return;
    const float di = dinv[node];
    float s = 0.0f;
#pragma unroll
    for (int h = 0; h < 2; ++h) {
        const int j = lane + 64 * h;
        float hv = fmaf(di, agg[(size_t)node * D_HID + j], b1[j]);
        hv = fmaxf(hv, 0.0f);
        s = fmaf(hv, W2[j], s);
    }
#pragma unroll
    for (int off = 32; off; off >>= 1) s += __shfl_down(s, off, 64);
    if (lane == 0) {
        const float zv = di * s;
        z[node] = zv;
        agg2[node] = zv;  // self-loop term
    }
}

// ---------------- layer 2 scatter: agg2[col] += z[row] (scalar) ---------------

__global__ void k_scatter2(const int* __restrict__ row, const int* __restrict__ col,
                           const float* __restrict__ z, float* __restrict__ agg2, int e) {
    const int i = blockIdx.x * blockDim.x + threadIdx.x;
    if (i < e) unsafeAtomicAdd(&agg2[col[i]], z[row[i]]);
}

// ---------------- final: sigmoid(relu(dinv*agg2 + b2)) -----------------------

__global__ void k_final(const float* __restrict__ agg2, const float* __restrict__ dinv,
                        const float* __restrict__ b2, float* __restrict__ out, int n) {
    const int i = blockIdx.x * blockDim.x + threadIdx.x;
    if (i < n) {
        float v = fmaf(dinv[i], agg2[i], b2[0]);
        v = fmaxf(v, 0.0f);              // relu before sigmoid (reference)
        out[i] = 1.0f / (1.0f + expf(-v));
    }
}

extern "C" void kernel_launch(void* const* d_in, const int* in_sizes, int n_in,
                              void* d_out, int out_size, void* d_ws, size_t ws_size,
                              hipStream_t stream) {
    const float* x  = (const float*)d_in[0];
    const int* ei   = (const int*)d_in[1];   // [2, E] int32
    const float* W1 = (const float*)d_in[2];
    const float* b1 = (const float*)d_in[3];
    const float* W2 = (const float*)d_in[4];
    const float* b2 = (const float*)d_in[5];
    float* out = (float*)d_out;

    const int* row = ei;             // edge_index[0]
    const int* col = ei + N_EDGES;   // edge_index[1]

    // workspace layout (floats)
    float* ws = (float*)d_ws;
    float* deg  = ws;                                   // N  (becomes dinv in-place)
    float* y    = deg + N_NODES;                        // N*128
    float* agg  = y + (size_t)N_NODES * D_HID;          // N*128
    float* z    = agg + (size_t)N_NODES * D_HID;        // N
    float* agg2 = z + N_NODES;                          // N
    float* dinv = deg;

    k_init_deg<<<(N_NODES + 255) / 256, 256, 0, stream>>>(deg, N_NODES);
    k_count<<<(N_EDGES + 255) / 256, 256, 0, stream>>>(col, deg, N_EDGES);
    k_dinv<<<(N_NODES + 255) / 256, 256, 0, stream>>>(deg, N_NODES);

    k_xw<<<N_NODES, D_HID, 0, stream>>>(x, W1, dinv, y, agg);

    {
        const long long threads = (long long)N_EDGES * 64;
        k_scatter<<<(int)((threads + 255) / 256), 256, 0, stream>>>(row, col, y, agg);
    }

    {
        const long long threads = (long long)N_NODES * 64;
        k_finish1<<<(int)((threads + 255) / 256), 256, 0, stream>>>(agg, dinv, b1, W2, z, agg2);
    }

    k_scatter2<<<(N_EDGES + 255) / 256, 256, 0, stream>>>(row, col, z, agg2, N_EDGES);

    k_final<<<(N_NODES + 255) / 256, 256, 0, stream>>>(agg2, dinv, b2, out, N_NODES);
}

// Round 2
// 630.284 us; speedup vs baseline: 2.5075x; 2.5075x over previous
//
#include <hip/hip_runtime.h>
#include <math.h>

#define N_NODES 100000
#define N_EDGES 1600000
#define D_IN 64
#define D_HID 128
#define SCAN_T 512

// ---------------- CSR build: histogram -> scan -> fill ----------------

__global__ void k_zero(int* __restrict__ cnt, int n) {
    int i = blockIdx.x * blockDim.x + threadIdx.x;
    if (i < n) cnt[i] = 0;
}

__global__ void k_hist(const int* __restrict__ col, int* __restrict__ cnt, int e) {
    int i = blockIdx.x * blockDim.x + threadIdx.x;
    if (i < e) atomicAdd(&cnt[col[i]], 1);
}

// single-block two-level exclusive scan: offsets[0..n], offsets[n] = total
__global__ void k_scan(const int* __restrict__ cnt, int* __restrict__ offsets, int n) {
    __shared__ int sm[SCAN_T];
    const int tid = threadIdx.x;
    const int chunk = (n + SCAN_T - 1) / SCAN_T;
    const int begin = tid * chunk;
    const int end = min(begin + chunk, n);
    int s = 0;
    for (int i = begin; i < end; ++i) s += cnt[i];
    sm[tid] = s;
    __syncthreads();
    for (int off = 1; off < SCAN_T; off <<= 1) {
        int t = (tid >= off) ? sm[tid - off] : 0;
        __syncthreads();
        sm[tid] += t;
        __syncthreads();
    }
    int run = sm[tid] - s;  // exclusive prefix
    for (int i = begin; i < end; ++i) {
        offsets[i] = run;
        run += cnt[i];
    }
    if (begin < n && end == n) offsets[n] = run;
}

// dinv = rsqrt(deg+1) (self-loop), cursor = offsets copy
__global__ void k_dinv_cursor(const int* __restrict__ cnt, const int* __restrict__ offsets,
                              float* __restrict__ dinv, int* __restrict__ cursor, int n) {
    int i = blockIdx.x * blockDim.x + threadIdx.x;
    if (i < n) {
        dinv[i] = rsqrtf((float)cnt[i] + 1.0f);
        cursor[i] = offsets[i];
    }
}

__global__ void k_fill(const int* __restrict__ row, const int* __restrict__ col,
                       int* __restrict__ cursor, int* __restrict__ src, int e) {
    int i = blockIdx.x * blockDim.x + threadIdx.x;
    if (i < e) {
        int c = col[i];
        int pos = atomicAdd(&cursor[c], 1);
        src[pos] = row[i];
    }
}

// ---------------- layer 1: y = dinv * (|x| @ W1) ----------------

__global__ void k_xw(const float* __restrict__ x, const float* __restrict__ W1,
                     const float* __restrict__ dinv, float* __restrict__ y) {
    __shared__ float xs[D_IN];
    const int node = blockIdx.x;
    const int j = threadIdx.x;  // 0..127
    if (j < D_IN) xs[j] = fabsf(x[(size_t)node * D_IN + j]);
    __syncthreads();
    float acc = 0.0f;
#pragma unroll
    for (int k = 0; k < D_IN; ++k) acc = fmaf(xs[k], W1[k * D_HID + j], acc);
    y[(size_t)node * D_HID + j] = dinv[node] * acc;
}

// ---------------- layer 1 aggregate (gather, no atomics) + epilogue fused ----
// acc = y[node] + sum_{in-edges} y[src]; h = relu(dinv*acc + b1); z = dinv*(h.W2)

__global__ void k_agg(const int* __restrict__ offsets, const int* __restrict__ src,
                      const float* __restrict__ y, const float* __restrict__ dinv,
                      const float* __restrict__ b1, const float* __restrict__ W2,
                      float* __restrict__ z) {
    const int t = blockIdx.x * blockDim.x + threadIdx.x;
    const int node = t >> 6;  // one wave per node
    const int lane = t & 63;
    if (node >= N_NODES) return;
    const float di = dinv[node];
    float2 acc = ((const float2*)(y + (size_t)node * D_HID))[lane];  // self-loop
    const int s0 = offsets[node], s1 = offsets[node + 1];
    for (int j = s0; j < s1; ++j) {
        const int r = src[j];
        const float2 v = ((const float2*)(y + (size_t)r * D_HID))[lane];
        acc.x += v.x;
        acc.y += v.y;
    }
    const float h0 = fmaxf(fmaf(di, acc.x, b1[2 * lane]), 0.0f);
    const float h1 = fmaxf(fmaf(di, acc.y, b1[2 * lane + 1]), 0.0f);
    float sv = fmaf(h0, W2[2 * lane], h1 * W2[2 * lane + 1]);
#pragma unroll
    for (int off = 32; off; off >>= 1) sv += __shfl_down(sv, off, 64);
    if (lane == 0) z[node] = di * sv;
}

// ---------------- layer 2 aggregate + final: sigmoid(relu(dinv*sum + b2)) ----

__global__ void k_out(const int* __restrict__ offsets, const int* __restrict__ src,
                      const float* __restrict__ z, const float* __restrict__ dinv,
                      const float* __restrict__ b2, float* __restrict__ out, int n) {
    const int i = blockIdx.x * blockDim.x + threadIdx.x;
    if (i >= n) return;
    float s = z[i];  // self-loop
    const int s0 = offsets[i], s1 = offsets[i + 1];
    for (int j = s0; j < s1; ++j) s += z[src[j]];
    float v = fmaf(dinv[i], s, b2[0]);
    v = fmaxf(v, 0.0f);
    out[i] = 1.0f / (1.0f + expf(-v));
}

extern "C" void kernel_launch(void* const* d_in, const int* in_sizes, int n_in,
                              void* d_out, int out_size, void* d_ws, size_t ws_size,
                              hipStream_t stream) {
    const float* x  = (const float*)d_in[0];
    const int* ei   = (const int*)d_in[1];   // [2, E] int32
    const float* W1 = (const float*)d_in[2];
    const float* b1 = (const float*)d_in[3];
    const float* W2 = (const float*)d_in[4];
    const float* b2 = (const float*)d_in[5];
    float* out = (float*)d_out;

    const int* row = ei;
    const int* col = ei + N_EDGES;

    // workspace layout
    char* p = (char*)d_ws;
    float* dinv   = (float*)p;               p += sizeof(float) * N_NODES;
    float* y      = (float*)p;               p += sizeof(float) * (size_t)N_NODES * D_HID;
    float* z      = (float*)p;               p += sizeof(float) * N_NODES;
    int* cnt      = (int*)p;                 p += sizeof(int) * N_NODES;
    int* offsets  = (int*)p;                 p += sizeof(int) * (N_NODES + 1);
    int* cursor   = (int*)p;                 p += sizeof(int) * (N_NODES + 1);
    int* src      = (int*)p;                 p += sizeof(int) * N_EDGES;

    k_zero<<<(N_NODES + 255) / 256, 256, 0, stream>>>(cnt, N_NODES);
    k_hist<<<(N_EDGES + 255) / 256, 256, 0, stream>>>(col, cnt, N_EDGES);
    k_scan<<<1, SCAN_T, 0, stream>>>(cnt, offsets, N_NODES);
    k_dinv_cursor<<<(N_NODES + 255) / 256, 256, 0, stream>>>(cnt, offsets, dinv, cursor, N_NODES);
    k_fill<<<(N_EDGES + 255) / 256, 256, 0, stream>>>(row, col, cursor, src, N_EDGES);

    k_xw<<<N_NODES, D_HID, 0, stream>>>(x, W1, dinv, y);

    {
        const long long threads = (long long)N_NODES * 64;
        k_agg<<<(int)((threads + 255) / 256), 256, 0, stream>>>(offsets, src, y, dinv, b1, W2, z);
    }

    k_out<<<(N_NODES + 255) / 256, 256, 0, stream>>>(offsets, src, z, dinv, b2, out, N_NODES);
}

// Round 3
// 466.543 us; speedup vs baseline: 3.3876x; 1.3510x over previous
//
#include <hip/hip_runtime.h>
#include <math.h>

#define N_NODES 100000
#define N_EDGES 1600000
#define D_IN 64
#define D_HID 128
#define SCAN_CHUNK 1024
#define SCAN_NBLK ((N_NODES + SCAN_CHUNK - 1) / SCAN_CHUNK)  // 98

static __device__ __forceinline__ unsigned short f2bf(float f) {
    unsigned int u = __float_as_uint(f);
    u += 0x7FFFu + ((u >> 16) & 1u);  // round-to-nearest-even
    return (unsigned short)(u >> 16);
}

// ---------------- CSR build ----------------

__global__ void k_zero(int* __restrict__ cnt, int n) {
    int i = blockIdx.x * blockDim.x + threadIdx.x;
    if (i < n) cnt[i] = 0;
}

__global__ void k_hist(const int* __restrict__ col, int* __restrict__ cnt, int e) {
    int i = blockIdx.x * blockDim.x + threadIdx.x;
    if (i < e) atomicAdd(&cnt[col[i]], 1);
}

// Phase A: per-block sums of 1024-element chunks
__global__ void k_scanA(const int* __restrict__ cnt, int* __restrict__ bsum, int n) {
    __shared__ int sm[256];
    const int b = blockIdx.x, t = threadIdx.x;
    int s = 0;
#pragma unroll
    for (int k = 0; k < 4; ++k) {
        int i = b * SCAN_CHUNK + t * 4 + k;
        if (i < n) s += cnt[i];
    }
    sm[t] = s;
    __syncthreads();
    for (int off = 128; off; off >>= 1) {
        if (t < off) sm[t] += sm[t + off];
        __syncthreads();
    }
    if (t == 0) bsum[b] = sm[0];
}

// Phase B: single block scans the 98 block sums; writes offsets[N]=total
__global__ void k_scanB(const int* __restrict__ bsum, int* __restrict__ bpre,
                        int* __restrict__ offsets) {
    __shared__ int sm[128];
    const int t = threadIdx.x;
    int s = (t < SCAN_NBLK) ? bsum[t] : 0;
    sm[t] = s;
    __syncthreads();
    for (int off = 1; off < 128; off <<= 1) {
        int v = (t >= off) ? sm[t - off] : 0;
        __syncthreads();
        sm[t] += v;
        __syncthreads();
    }
    if (t < SCAN_NBLK) bpre[t] = sm[t] - s;
    if (t == 127) offsets[N_NODES] = sm[127];
}

// Phase C: final offsets + cursor copy + dinv, fused
__global__ void k_scanC(const int* __restrict__ cnt, const int* __restrict__ bpre,
                        int* __restrict__ offsets, int* __restrict__ cursor,
                        float* __restrict__ dinv, int n) {
    __shared__ int sm[256];
    const int b = blockIdx.x, t = threadIdx.x;
    int c[4];
    int s = 0;
#pragma unroll
    for (int k = 0; k < 4; ++k) {
        int i = b * SCAN_CHUNK + t * 4 + k;
        c[k] = (i < n) ? cnt[i] : 0;
        s += c[k];
    }
    sm[t] = s;
    __syncthreads();
    for (int off = 1; off < 256; off <<= 1) {
        int v = (t >= off) ? sm[t - off] : 0;
        __syncthreads();
        sm[t] += v;
        __syncthreads();
    }
    int run = bpre[b] + sm[t] - s;  // exclusive prefix for this thread's 4 elems
#pragma unroll
    for (int k = 0; k < 4; ++k) {
        int i = b * SCAN_CHUNK + t * 4 + k;
        if (i < n) {
            offsets[i] = run;
            cursor[i] = run;
            dinv[i] = rsqrtf((float)c[k] + 1.0f);
            run += c[k];
        }
    }
}

__global__ void k_fill(const int* __restrict__ row, const int* __restrict__ col,
                       int* __restrict__ cursor, int* __restrict__ src, int e) {
    int i = blockIdx.x * blockDim.x + threadIdx.x;
    if (i < e) {
        int c = col[i];
        int pos = atomicAdd(&cursor[c], 1);
        src[pos] = row[i];
    }
}

// ---------------- layer 1: y = bf16(dinv * (|x| @ W1)) ----------------

__global__ void k_xw(const float* __restrict__ x, const float* __restrict__ W1,
                     const float* __restrict__ dinv, unsigned short* __restrict__ y) {
    __shared__ float xs[D_IN];
    const int node = blockIdx.x;
    const int j = threadIdx.x;  // 0..127
    if (j < D_IN) xs[j] = fabsf(x[(size_t)node * D_IN + j]);
    __syncthreads();
    float acc = 0.0f;
#pragma unroll
    for (int k = 0; k < D_IN; ++k) acc = fmaf(xs[k], W1[k * D_HID + j], acc);
    y[(size_t)node * D_HID + j] = f2bf(dinv[node] * acc);
}

// ---------------- layer 1 aggregate (gather bf16) + epilogue fused ----------
// acc = y[node] + sum y[src]; h = relu(dinv*acc + b1); z = dinv*(h.W2)

__global__ void k_agg(const int* __restrict__ offsets, const int* __restrict__ src,
                      const unsigned short* __restrict__ y, const float* __restrict__ dinv,
                      const float* __restrict__ b1, const float* __restrict__ W2,
                      float* __restrict__ z) {
    const int t = blockIdx.x * blockDim.x + threadIdx.x;
    const int node = t >> 6;  // one wave per node
    const int lane = t & 63;
    if (node >= N_NODES) return;
    const float di = dinv[node];
    unsigned int v0 = ((const unsigned int*)(y + (size_t)node * D_HID))[lane];  // self
    float ax = __uint_as_float(v0 << 16);
    float ay = __uint_as_float(v0 & 0xFFFF0000u);
    const int s0 = offsets[node], s1 = offsets[node + 1];
    for (int j = s0; j < s1; ++j) {
        const int r = src[j];
        const unsigned int v = ((const unsigned int*)(y + (size_t)r * D_HID))[lane];
        ax += __uint_as_float(v << 16);
        ay += __uint_as_float(v & 0xFFFF0000u);
    }
    const float h0 = fmaxf(fmaf(di, ax, b1[2 * lane]), 0.0f);
    const float h1 = fmaxf(fmaf(di, ay, b1[2 * lane + 1]), 0.0f);
    float sv = fmaf(h0, W2[2 * lane], h1 * W2[2 * lane + 1]);
#pragma unroll
    for (int off = 32; off; off >>= 1) sv += __shfl_down(sv, off, 64);
    if (lane == 0) z[node] = di * sv;
}

// ---------------- layer 2 aggregate + final ----------------

__global__ void k_out(const int* __restrict__ offsets, const int* __restrict__ src,
                      const float* __restrict__ z, const float* __restrict__ dinv,
                      const float* __restrict__ b2, float* __restrict__ out, int n) {
    const int i = blockIdx.x * blockDim.x + threadIdx.x;
    if (i >= n) return;
    float s = z[i];  // self-loop
    const int s0 = offsets[i], s1 = offsets[i + 1];
    for (int j = s0; j < s1; ++j) s += z[src[j]];
    float v = fmaf(dinv[i], s, b2[0]);
    v = fmaxf(v, 0.0f);
    out[i] = 1.0f / (1.0f + expf(-v));
}

extern "C" void kernel_launch(void* const* d_in, const int* in_sizes, int n_in,
                              void* d_out, int out_size, void* d_ws, size_t ws_size,
                              hipStream_t stream) {
    const float* x  = (const float*)d_in[0];
    const int* ei   = (const int*)d_in[1];
    const float* W1 = (const float*)d_in[2];
    const float* b1 = (const float*)d_in[3];
    const float* W2 = (const float*)d_in[4];
    const float* b2 = (const float*)d_in[5];
    float* out = (float*)d_out;

    const int* row = ei;
    const int* col = ei + N_EDGES;

    // workspace layout
    char* p = (char*)d_ws;
    float* dinv          = (float*)p;          p += sizeof(float) * N_NODES;
    unsigned short* y    = (unsigned short*)p; p += sizeof(unsigned short) * (size_t)N_NODES * D_HID;
    float* z             = (float*)p;          p += sizeof(float) * N_NODES;
    int* cnt             = (int*)p;            p += sizeof(int) * N_NODES;
    int* offsets         = (int*)p;            p += sizeof(int) * (N_NODES + 1);
    int* cursor          = (int*)p;            p += sizeof(int) * (N_NODES + 1);
    int* src             = (int*)p;            p += sizeof(int) * N_EDGES;
    int* bsum            = (int*)p;            p += sizeof(int) * SCAN_NBLK;
    int* bpre            = (int*)p;            p += sizeof(int) * SCAN_NBLK;

    k_zero<<<(N_NODES + 255) / 256, 256, 0, stream>>>(cnt, N_NODES);
    k_hist<<<(N_EDGES + 255) / 256, 256, 0, stream>>>(col, cnt, N_EDGES);
    k_scanA<<<SCAN_NBLK, 256, 0, stream>>>(cnt, bsum, N_NODES);
    k_scanB<<<1, 128, 0, stream>>>(bsum, bpre, offsets);
    k_scanC<<<SCAN_NBLK, 256, 0, stream>>>(cnt, bpre, offsets, cursor, dinv, N_NODES);
    k_fill<<<(N_EDGES + 255) / 256, 256, 0, stream>>>(row, col, cursor, src, N_EDGES);

    k_xw<<<N_NODES, D_HID, 0, stream>>>(x, W1, dinv, y);

    {
        const long long threads = (long long)N_NODES * 64;
        k_agg<<<(int)((threads + 255) / 256), 256, 0, stream>>>(offsets, src, y, dinv, b1, W2, z);
    }

    k_out<<<(N_NODES + 255) / 256, 256, 0, stream>>>(offsets, src, z, dinv, b2, out, N_NODES);
}

// Round 4
// 375.512 us; speedup vs baseline: 4.2088x; 1.2424x over previous
//
#include <hip/hip_runtime.h>
#include <math.h>

#define N_NODES 100000
#define N_EDGES 1600000
#define D_IN 64
#define D_HID 128
#define SCAN_CHUNK 1024
#define SCAN_NBLK ((N_NODES + SCAN_CHUNK - 1) / SCAN_CHUNK)  // 98

static __device__ __forceinline__ unsigned short f2bf(float f) {
    unsigned int u = __float_as_uint(f);
    u += 0x7FFFu + ((u >> 16) & 1u);  // round-to-nearest-even
    return (unsigned short)(u >> 16);
}

// ---------------- CSR build ----------------

__global__ void k_zero(int* __restrict__ cnt, int n) {
    int i = blockIdx.x * blockDim.x + threadIdx.x;
    if (i < n) cnt[i] = 0;
}

__global__ void k_hist(const int* __restrict__ col, int* __restrict__ cnt, int e) {
    int i = blockIdx.x * blockDim.x + threadIdx.x;
    if (i < e) atomicAdd(&cnt[col[i]], 1);
}

// Phase A: per-block sums of 1024-element chunks
__global__ void k_scanA(const int* __restrict__ cnt, int* __restrict__ bsum, int n) {
    __shared__ int sm[256];
    const int b = blockIdx.x, t = threadIdx.x;
    int s = 0;
#pragma unroll
    for (int k = 0; k < 4; ++k) {
        int i = b * SCAN_CHUNK + t * 4 + k;
        if (i < n) s += cnt[i];
    }
    sm[t] = s;
    __syncthreads();
    for (int off = 128; off; off >>= 1) {
        if (t < off) sm[t] += sm[t + off];
        __syncthreads();
    }
    if (t == 0) bsum[b] = sm[0];
}

// Phase B: single block scans the block sums; writes offsets[N]=total
__global__ void k_scanB(const int* __restrict__ bsum, int* __restrict__ bpre,
                        int* __restrict__ offsets) {
    __shared__ int sm[128];
    const int t = threadIdx.x;
    int s = (t < SCAN_NBLK) ? bsum[t] : 0;
    sm[t] = s;
    __syncthreads();
    for (int off = 1; off < 128; off <<= 1) {
        int v = (t >= off) ? sm[t - off] : 0;
        __syncthreads();
        sm[t] += v;
        __syncthreads();
    }
    if (t < SCAN_NBLK) bpre[t] = sm[t] - s;
    if (t == 127) offsets[N_NODES] = sm[127];
}

// Phase C: final offsets + cursor copy + dinv, fused
__global__ void k_scanC(const int* __restrict__ cnt, const int* __restrict__ bpre,
                        int* __restrict__ offsets, int* __restrict__ cursor,
                        float* __restrict__ dinv, int n) {
    __shared__ int sm[256];
    const int b = blockIdx.x, t = threadIdx.x;
    int c[4];
    int s = 0;
#pragma unroll
    for (int k = 0; k < 4; ++k) {
        int i = b * SCAN_CHUNK + t * 4 + k;
        c[k] = (i < n) ? cnt[i] : 0;
        s += c[k];
    }
    sm[t] = s;
    __syncthreads();
    for (int off = 1; off < 256; off <<= 1) {
        int v = (t >= off) ? sm[t - off] : 0;
        __syncthreads();
        sm[t] += v;
        __syncthreads();
    }
    int run = bpre[b] + sm[t] - s;
#pragma unroll
    for (int k = 0; k < 4; ++k) {
        int i = b * SCAN_CHUNK + t * 4 + k;
        if (i < n) {
            offsets[i] = run;
            cursor[i] = run;
            dinv[i] = rsqrtf((float)c[k] + 1.0f);
            run += c[k];
        }
    }
}

__global__ void k_fill(const int* __restrict__ row, const int* __restrict__ col,
                       int* __restrict__ cursor, int* __restrict__ src, int e) {
    int i = blockIdx.x * blockDim.x + threadIdx.x;
    if (i < e) {
        int c = col[i];
        int pos = atomicAdd(&cursor[c], 1);
        src[pos] = row[i];
    }
}

// ---------------- layer 1: y = bf16(dinv * (|x| @ W1)) ----------------

__global__ void k_xw(const float* __restrict__ x, const float* __restrict__ W1,
                     const float* __restrict__ dinv, unsigned short* __restrict__ y) {
    __shared__ float xs[D_IN];
    const int node = blockIdx.x;
    const int j = threadIdx.x;  // 0..127
    if (j < D_IN) xs[j] = fabsf(x[(size_t)node * D_IN + j]);
    __syncthreads();
    float acc = 0.0f;
#pragma unroll
    for (int k = 0; k < D_IN; ++k) acc = fmaf(xs[k], W1[k * D_HID + j], acc);
    y[(size_t)node * D_HID + j] = f2bf(dinv[node] * acc);
}

// ---------------- layer 1 aggregate: 4 edge-groups x 16 dim-lanes, uint4 loads --
// acc = y[node] + sum y[src]; h = relu(dinv*acc + b1); z = dinv*(h.W2)

#define ACC8(v)                                                 \
    do {                                                        \
        a0 += __uint_as_float((v).x << 16);                     \
        a1 += __uint_as_float((v).x & 0xFFFF0000u);             \
        a2 += __uint_as_float((v).y << 16);                     \
        a3 += __uint_as_float((v).y & 0xFFFF0000u);             \
        a4 += __uint_as_float((v).z << 16);                     \
        a5 += __uint_as_float((v).z & 0xFFFF0000u);             \
        a6 += __uint_as_float((v).w << 16);                     \
        a7 += __uint_as_float((v).w & 0xFFFF0000u);             \
    } while (0)

__global__ void k_agg(const int* __restrict__ offsets, const int* __restrict__ src,
                      const unsigned short* __restrict__ y, const float* __restrict__ dinv,
                      const float* __restrict__ b1, const float* __restrict__ W2,
                      float* __restrict__ z) {
    const int t = blockIdx.x * blockDim.x + threadIdx.x;
    const int node = t >> 6;  // one wave per node
    const int lane = t & 63;
    if (node >= N_NODES) return;
    const int eg = lane >> 4;  // edge group 0..3
    const int dc = lane & 15;  // dim chunk: dims 8*dc .. 8*dc+7

    float a0 = 0, a1 = 0, a2 = 0, a3 = 0, a4 = 0, a5 = 0, a6 = 0, a7 = 0;

    if (eg == 0) {  // self-loop term, counted once
        const uint4 v = ((const uint4*)(y + (size_t)node * D_HID))[dc];
        ACC8(v);
    }

    const int s0 = offsets[node], s1 = offsets[node + 1];
    int j = s0 + eg;
    for (; j + 4 < s1; j += 8) {  // 2x unrolled: 8 gathers in flight per wave
        const int r0 = src[j];
        const int r1 = src[j + 4];
        const uint4 v0 = ((const uint4*)(y + (size_t)r0 * D_HID))[dc];
        const uint4 v1 = ((const uint4*)(y + (size_t)r1 * D_HID))[dc];
        ACC8(v0);
        ACC8(v1);
    }
    if (j < s1) {
        const int r = src[j];
        const uint4 v = ((const uint4*)(y + (size_t)r * D_HID))[dc];
        ACC8(v);
    }

    // reduce across the 4 edge groups (butterfly over lane bits 4,5)
#pragma unroll
    for (int m = 16; m <= 32; m <<= 1) {
        a0 += __shfl_xor(a0, m, 64);
        a1 += __shfl_xor(a1, m, 64);
        a2 += __shfl_xor(a2, m, 64);
        a3 += __shfl_xor(a3, m, 64);
        a4 += __shfl_xor(a4, m, 64);
        a5 += __shfl_xor(a5, m, 64);
        a6 += __shfl_xor(a6, m, 64);
        a7 += __shfl_xor(a7, m, 64);
    }

    // epilogue: h = relu(di*a + b1), sv = h . W2 over this lane's 8 dims
    const float di = dinv[node];
    const float4 b1a = ((const float4*)(b1 + 8 * dc))[0];
    const float4 b1b = ((const float4*)(b1 + 8 * dc))[1];
    const float4 w2a = ((const float4*)(W2 + 8 * dc))[0];
    const float4 w2b = ((const float4*)(W2 + 8 * dc))[1];
    float sv;
    {
        float h;
        h = fmaxf(fmaf(di, a0, b1a.x), 0.0f); sv = h * w2a.x;
        h = fmaxf(fmaf(di, a1, b1a.y), 0.0f); sv = fmaf(h, w2a.y, sv);
        h = fmaxf(fmaf(di, a2, b1a.z), 0.0f); sv = fmaf(h, w2a.z, sv);
        h = fmaxf(fmaf(di, a3, b1a.w), 0.0f); sv = fmaf(h, w2a.w, sv);
        h = fmaxf(fmaf(di, a4, b1b.x), 0.0f); sv = fmaf(h, w2b.x, sv);
        h = fmaxf(fmaf(di, a5, b1b.y), 0.0f); sv = fmaf(h, w2b.y, sv);
        h = fmaxf(fmaf(di, a6, b1b.z), 0.0f); sv = fmaf(h, w2b.z, sv);
        h = fmaxf(fmaf(di, a7, b1b.w), 0.0f); sv = fmaf(h, w2b.w, sv);
    }
    // reduce across the 16 dim chunks (lane bits 0..3); eg groups hold duplicates
#pragma unroll
    for (int m = 1; m <= 8; m <<= 1) sv += __shfl_xor(sv, m, 64);
    if (lane == 0) z[node] = di * sv;
}

// ---------------- layer 2 aggregate + final ----------------

__global__ void k_out(const int* __restrict__ offsets, const int* __restrict__ src,
                      const float* __restrict__ z, const float* __restrict__ dinv,
                      const float* __restrict__ b2, float* __restrict__ out, int n) {
    const int i = blockIdx.x * blockDim.x + threadIdx.x;
    if (i >= n) return;
    float s = z[i];  // self-loop
    const int s0 = offsets[i], s1 = offsets[i + 1];
    for (int j = s0; j < s1; ++j) s += z[src[j]];
    float v = fmaf(dinv[i], s, b2[0]);
    v = fmaxf(v, 0.0f);
    out[i] = 1.0f / (1.0f + expf(-v));
}

extern "C" void kernel_launch(void* const* d_in, const int* in_sizes, int n_in,
                              void* d_out, int out_size, void* d_ws, size_t ws_size,
                              hipStream_t stream) {
    const float* x  = (const float*)d_in[0];
    const int* ei   = (const int*)d_in[1];
    const float* W1 = (const float*)d_in[2];
    const float* b1 = (const float*)d_in[3];
    const float* W2 = (const float*)d_in[4];
    const float* b2 = (const float*)d_in[5];
    float* out = (float*)d_out;

    const int* row = ei;
    const int* col = ei + N_EDGES;

    // workspace layout
    char* p = (char*)d_ws;
    float* dinv          = (float*)p;          p += sizeof(float) * N_NODES;
    unsigned short* y    = (unsigned short*)p; p += sizeof(unsigned short) * (size_t)N_NODES * D_HID;
    float* z             = (float*)p;          p += sizeof(float) * N_NODES;
    int* cnt             = (int*)p;            p += sizeof(int) * N_NODES;
    int* offsets         = (int*)p;            p += sizeof(int) * (N_NODES + 1);
    int* cursor          = (int*)p;            p += sizeof(int) * (N_NODES + 1);
    int* src             = (int*)p;            p += sizeof(int) * N_EDGES;
    int* bsum            = (int*)p;            p += sizeof(int) * SCAN_NBLK;
    int* bpre            = (int*)p;            p += sizeof(int) * SCAN_NBLK;

    k_zero<<<(N_NODES + 255) / 256, 256, 0, stream>>>(cnt, N_NODES);
    k_hist<<<(N_EDGES + 255) / 256, 256, 0, stream>>>(col, cnt, N_EDGES);
    k_scanA<<<SCAN_NBLK, 256, 0, stream>>>(cnt, bsum, N_NODES);
    k_scanB<<<1, 128, 0, stream>>>(bsum, bpre, offsets);
    k_scanC<<<SCAN_NBLK, 256, 0, stream>>>(cnt, bpre, offsets, cursor, dinv, N_NODES);
    k_fill<<<(N_EDGES + 255) / 256, 256, 0, stream>>>(row, col, cursor, src, N_EDGES);

    k_xw<<<N_NODES, D_HID, 0, stream>>>(x, W1, dinv, y);

    {
        const long long threads = (long long)N_NODES * 64;
        k_agg<<<(int)((threads + 255) / 256), 256, 0, stream>>>(offsets, src, y, dinv, b1, W2, z);
    }

    k_out<<<(N_NODES + 255) / 256, 256, 0, stream>>>(offsets, src, z, dinv, b2, out, N_NODES);
}

// Round 5
// 222.802 us; speedup vs baseline: 7.0936x; 1.6854x over previous
//
#include <hip/hip_runtime.h>
#include <math.h>

#define N_NODES 100000
#define N_EDGES 1600000
#define D_IN 64
#define D_HID 128

#define BKT_SHIFT 9
#define BKT_NODES 512
#define NB ((N_NODES + BKT_NODES - 1) / BKT_NODES)  // 196
#define CAP 16384                                    // per-bucket pair capacity (mean ~8163)
#define CHUNK 4096
#define BIN_T 512

static __device__ __forceinline__ unsigned short f2bf(float f) {
    unsigned int u = __float_as_uint(f);
    u += 0x7FFFu + ((u >> 16) & 1u);  // round-to-nearest-even
    return (unsigned short)(u >> 16);
}

// ---------------- tiny init ----------------

__global__ void k_zero(int* __restrict__ p, int n) {
    int i = blockIdx.x * blockDim.x + threadIdx.x;
    if (i < n) p[i] = 0;
}

// ---------------- phase 1: LDS counting-sort edges into 196 col-buckets ------

__global__ __launch_bounds__(BIN_T) void k_bin(const int* __restrict__ row,
                                               const int* __restrict__ col,
                                               int* __restrict__ gcur,
                                               uint2* __restrict__ pairs) {
    __shared__ int bcnt[NB];
    __shared__ int boff[NB];
    __shared__ int gbase[NB];
    __shared__ int sc[256];
    __shared__ uint2 stage[CHUNK];
    const int t = threadIdx.x;
    const int e0 = blockIdx.x * CHUNK;
    const int nE = min(CHUNK, N_EDGES - e0);

    for (int i = t; i < NB; i += BIN_T) bcnt[i] = 0;
    __syncthreads();

    int myb[8], myrank[8], myr[8], myc[8];
#pragma unroll
    for (int k = 0; k < 8; ++k) {
        const int i = t + k * BIN_T;
        if (i < nE) {
            myr[k] = row[e0 + i];
            myc[k] = col[e0 + i];
            myb[k] = myc[k] >> BKT_SHIFT;
            myrank[k] = atomicAdd(&bcnt[myb[k]], 1);
        }
    }
    __syncthreads();

    // exclusive scan of bcnt (NB<=256) with first 256 threads
    if (t < 256) {
        sc[t] = (t < NB) ? bcnt[t] : 0;
    }
    __syncthreads();
    for (int off = 1; off < 256; off <<= 1) {
        int v = 0;
        if (t < 256 && t >= off) v = sc[t - off];
        __syncthreads();
        if (t < 256) sc[t] += v;
        __syncthreads();
    }
    if (t < NB) {
        boff[t] = sc[t] - bcnt[t];
        if (bcnt[t] > 0) gbase[t] = atomicAdd(&gcur[t], bcnt[t]);
    }
    __syncthreads();

    // stage into bucket-sorted order in LDS
#pragma unroll
    for (int k = 0; k < 8; ++k) {
        const int i = t + k * BIN_T;
        if (i < nE)
            stage[boff[myb[k]] + myrank[k]] = make_uint2((unsigned)myr[k], (unsigned)myc[k]);
    }
    __syncthreads();

    // copy out: bucket-contiguous runs -> dense global writes
    for (int s = t; s < nE; s += BIN_T) {
        const uint2 p = stage[s];
        const int b = (int)(p.y >> BKT_SHIFT);
        pairs[(size_t)b * CAP + gbase[b] + (s - boff[b])] = p;
    }
}

// ---------------- bucket bases: exclusive scan of 196 bucket counts ----------

__global__ void k_bases(const int* __restrict__ gcur, int* __restrict__ bbase,
                        int* __restrict__ offsets) {
    __shared__ int sc[256];
    const int t = threadIdx.x;
    const int v = (t < NB) ? gcur[t] : 0;
    sc[t] = v;
    __syncthreads();
    for (int off = 1; off < 256; off <<= 1) {
        int u = (t >= off) ? sc[t - off] : 0;
        __syncthreads();
        sc[t] += u;
        __syncthreads();
    }
    if (t < NB) bbase[t] = sc[t] - v;
    if (t == 255) offsets[N_NODES] = sc[255];
}

// ---------------- phase 2: per-bucket node hist + scan + dense fill ----------

__global__ void k_fill2(const uint2* __restrict__ pairs, const int* __restrict__ gcur,
                        const int* __restrict__ bbase, int* __restrict__ offsets,
                        float* __restrict__ dinv, int* __restrict__ src) {
    __shared__ int ncnt[BKT_NODES];
    __shared__ int ncur[BKT_NODES];
    __shared__ int sc[256];
    const int b = blockIdx.x, t = threadIdx.x;
    const int base = b << BKT_SHIFT;
    const int nNodes = min(BKT_NODES, N_NODES - base);
    const int nE = gcur[b];
    const int gb = bbase[b];
    const uint2* bp = pairs + (size_t)b * CAP;

    for (int i = t; i < BKT_NODES; i += 256) ncnt[i] = 0;
    __syncthreads();
    for (int i = t; i < nE; i += 256) atomicAdd(&ncnt[(int)bp[i].y - base], 1);
    __syncthreads();

    // scan 512 counters with 256 threads (2 per thread)
    const int c0 = ncnt[2 * t], c1 = ncnt[2 * t + 1];
    sc[t] = c0 + c1;
    __syncthreads();
    for (int off = 1; off < 256; off <<= 1) {
        int u = (t >= off) ? sc[t - off] : 0;
        __syncthreads();
        sc[t] += u;
        __syncthreads();
    }
    const int pre = sc[t] - (c0 + c1);
    const int o0 = gb + pre;
    const int o1 = o0 + c0;
    if (2 * t < nNodes) {
        offsets[base + 2 * t] = o0;
        dinv[base + 2 * t] = rsqrtf((float)c0 + 1.0f);
        ncur[2 * t] = o0;
    }
    if (2 * t + 1 < nNodes) {
        offsets[base + 2 * t + 1] = o1;
        dinv[base + 2 * t + 1] = rsqrtf((float)c1 + 1.0f);
        ncur[2 * t + 1] = o1;
    }
    __syncthreads();

    for (int i = t; i < nE; i += 256) {
        const uint2 p = bp[i];
        const int pos = atomicAdd(&ncur[(int)p.y - base], 1);
        src[pos] = (int)p.x;
    }
}

// ---------------- layer 1: y = bf16(dinv * (|x| @ W1)) ----------------

__global__ void k_xw(const float* __restrict__ x, const float* __restrict__ W1,
                     const float* __restrict__ dinv, unsigned short* __restrict__ y) {
    __shared__ float xs[D_IN];
    const int node = blockIdx.x;
    const int j = threadIdx.x;  // 0..127
    if (j < D_IN) xs[j] = fabsf(x[(size_t)node * D_IN + j]);
    __syncthreads();
    float acc = 0.0f;
#pragma unroll
    for (int k = 0; k < D_IN; ++k) acc = fmaf(xs[k], W1[k * D_HID + j], acc);
    y[(size_t)node * D_HID + j] = f2bf(dinv[node] * acc);
}

// ---------------- layer 1 aggregate: 4 edge-groups x 16 dim-lanes, uint4 loads --

#define ACC8(v)                                                 \
    do {                                                        \
        a0 += __uint_as_float((v).x << 16);                     \
        a1 += __uint_as_float((v).x & 0xFFFF0000u);             \
        a2 += __uint_as_float((v).y << 16);                     \
        a3 += __uint_as_float((v).y & 0xFFFF0000u);             \
        a4 += __uint_as_float((v).z << 16);                     \
        a5 += __uint_as_float((v).z & 0xFFFF0000u);             \
        a6 += __uint_as_float((v).w << 16);                     \
        a7 += __uint_as_float((v).w & 0xFFFF0000u);             \
    } while (0)

__global__ void k_agg(const int* __restrict__ offsets, const int* __restrict__ src,
                      const unsigned short* __restrict__ y, const float* __restrict__ dinv,
                      const float* __restrict__ b1, const float* __restrict__ W2,
                      float* __restrict__ z) {
    const int t = blockIdx.x * blockDim.x + threadIdx.x;
    const int node = t >> 6;  // one wave per node
    const int lane = t & 63;
    if (node >= N_NODES) return;
    const int eg = lane >> 4;  // edge group 0..3
    const int dc = lane & 15;  // dim chunk: dims 8*dc .. 8*dc+7

    float a0 = 0, a1 = 0, a2 = 0, a3 = 0, a4 = 0, a5 = 0, a6 = 0, a7 = 0;

    if (eg == 0) {  // self-loop term, counted once
        const uint4 v = ((const uint4*)(y + (size_t)node * D_HID))[dc];
        ACC8(v);
    }

    const int s0 = offsets[node], s1 = offsets[node + 1];
    int j = s0 + eg;
    for (; j + 4 < s1; j += 8) {  // 8 independent gathers in flight per wave
        const int r0 = src[j];
        const int r1 = src[j + 4];
        const uint4 v0 = ((const uint4*)(y + (size_t)r0 * D_HID))[dc];
        const uint4 v1 = ((const uint4*)(y + (size_t)r1 * D_HID))[dc];
        ACC8(v0);
        ACC8(v1);
    }
    if (j < s1) {
        const int r = src[j];
        const uint4 v = ((const uint4*)(y + (size_t)r * D_HID))[dc];
        ACC8(v);
    }

#pragma unroll
    for (int m = 16; m <= 32; m <<= 1) {
        a0 += __shfl_xor(a0, m, 64);
        a1 += __shfl_xor(a1, m, 64);
        a2 += __shfl_xor(a2, m, 64);
        a3 += __shfl_xor(a3, m, 64);
        a4 += __shfl_xor(a4, m, 64);
        a5 += __shfl_xor(a5, m, 64);
        a6 += __shfl_xor(a6, m, 64);
        a7 += __shfl_xor(a7, m, 64);
    }

    const float di = dinv[node];
    const float4 b1a = ((const float4*)(b1 + 8 * dc))[0];
    const float4 b1b = ((const float4*)(b1 + 8 * dc))[1];
    const float4 w2a = ((const float4*)(W2 + 8 * dc))[0];
    const float4 w2b = ((const float4*)(W2 + 8 * dc))[1];
    float sv;
    {
        float h;
        h = fmaxf(fmaf(di, a0, b1a.x), 0.0f); sv = h * w2a.x;
        h = fmaxf(fmaf(di, a1, b1a.y), 0.0f); sv = fmaf(h, w2a.y, sv);
        h = fmaxf(fmaf(di, a2, b1a.z), 0.0f); sv = fmaf(h, w2a.z, sv);
        h = fmaxf(fmaf(di, a3, b1a.w), 0.0f); sv = fmaf(h, w2a.w, sv);
        h = fmaxf(fmaf(di, a4, b1b.x), 0.0f); sv = fmaf(h, w2b.x, sv);
        h = fmaxf(fmaf(di, a5, b1b.y), 0.0f); sv = fmaf(h, w2b.y, sv);
        h = fmaxf(fmaf(di, a6, b1b.z), 0.0f); sv = fmaf(h, w2b.z, sv);
        h = fmaxf(fmaf(di, a7, b1b.w), 0.0f); sv = fmaf(h, w2b.w, sv);
    }
#pragma unroll
    for (int m = 1; m <= 8; m <<= 1) sv += __shfl_xor(sv, m, 64);
    if (lane == 0) z[node] = di * sv;
}

// ---------------- layer 2 aggregate + final ----------------

__global__ void k_out(const int* __restrict__ offsets, const int* __restrict__ src,
                      const float* __restrict__ z, const float* __restrict__ dinv,
                      const float* __restrict__ b2, float* __restrict__ out, int n) {
    const int i = blockIdx.x * blockDim.x + threadIdx.x;
    if (i >= n) return;
    float s = z[i];  // self-loop
    const int s0 = offsets[i], s1 = offsets[i + 1];
    for (int j = s0; j < s1; ++j) s += z[src[j]];
    float v = fmaf(dinv[i], s, b2[0]);
    v = fmaxf(v, 0.0f);
    out[i] = 1.0f / (1.0f + expf(-v));
}

extern "C" void kernel_launch(void* const* d_in, const int* in_sizes, int n_in,
                              void* d_out, int out_size, void* d_ws, size_t ws_size,
                              hipStream_t stream) {
    const float* x  = (const float*)d_in[0];
    const int* ei   = (const int*)d_in[1];
    const float* W1 = (const float*)d_in[2];
    const float* b1 = (const float*)d_in[3];
    const float* W2 = (const float*)d_in[4];
    const float* b2 = (const float*)d_in[5];
    float* out = (float*)d_out;

    const int* row = ei;
    const int* col = ei + N_EDGES;

    // workspace layout
    char* p = (char*)d_ws;
    float* dinv          = (float*)p;          p += sizeof(float) * N_NODES;
    unsigned short* y    = (unsigned short*)p; p += sizeof(unsigned short) * (size_t)N_NODES * D_HID;
    float* z             = (float*)p;          p += sizeof(float) * N_NODES;
    int* offsets         = (int*)p;            p += sizeof(int) * (N_NODES + 1);
    int* src             = (int*)p;            p += sizeof(int) * N_EDGES;
    int* gcur            = (int*)p;            p += sizeof(int) * NB;
    int* bbase           = (int*)p;            p += sizeof(int) * NB;
    p = (char*)(((size_t)p + 15) & ~(size_t)15);
    uint2* pairs         = (uint2*)p;          p += sizeof(uint2) * (size_t)NB * CAP;

    k_zero<<<1, 256, 0, stream>>>(gcur, NB);
    k_bin<<<(N_EDGES + CHUNK - 1) / CHUNK, BIN_T, 0, stream>>>(row, col, gcur, pairs);
    k_bases<<<1, 256, 0, stream>>>(gcur, bbase, offsets);
    k_fill2<<<NB, 256, 0, stream>>>(pairs, gcur, bbase, offsets, dinv, src);

    k_xw<<<N_NODES, D_HID, 0, stream>>>(x, W1, dinv, y);

    {
        const long long threads = (long long)N_NODES * 64;
        k_agg<<<(int)((threads + 255) / 256), 256, 0, stream>>>(offsets, src, y, dinv, b1, W2, z);
    }

    k_out<<<(N_NODES + 255) / 256, 256, 0, stream>>>(offsets, src, z, dinv, b2, out, N_NODES);
}

// Round 6
// 158.755 us; speedup vs baseline: 9.9553x; 1.4034x over previous
//
#include <hip/hip_runtime.h>
#include <math.h>

#define N_NODES 100000
#define N_EDGES 1600000
#define D_IN 64
#define D_HID 128

#define BKT_SHIFT 9
#define BKT_NODES 512
#define NB ((N_NODES + BKT_NODES - 1) / BKT_NODES)  // 196
#define CAP 16384                                    // per-bucket pair capacity (mean ~8163)
#define CHUNK 4096
#define BIN_T 512

#define XW_T 256
#define XW_NODES 128
#define XW_NBLK ((N_NODES + XW_NODES - 1) / XW_NODES)  // 782

static __device__ __forceinline__ unsigned short f2bf(float f) {
    unsigned int u = __float_as_uint(f);
    u += 0x7FFFu + ((u >> 16) & 1u);  // round-to-nearest-even
    return (unsigned short)(u >> 16);
}

// ---------------- tiny init ----------------

__global__ void k_zero(int* __restrict__ p, int n) {
    int i = blockIdx.x * blockDim.x + threadIdx.x;
    if (i < n) p[i] = 0;
}

// ---------------- phase 1: LDS counting-sort edges into 196 col-buckets ------

__global__ __launch_bounds__(BIN_T) void k_bin(const int* __restrict__ row,
                                               const int* __restrict__ col,
                                               int* __restrict__ gcur,
                                               uint2* __restrict__ pairs) {
    __shared__ int bcnt[NB];
    __shared__ int boff[NB];
    __shared__ int gbase[NB];
    __shared__ int sc[256];
    __shared__ uint2 stage[CHUNK];
    const int t = threadIdx.x;
    const int e0 = blockIdx.x * CHUNK;
    const int nE = min(CHUNK, N_EDGES - e0);

    for (int i = t; i < NB; i += BIN_T) bcnt[i] = 0;
    __syncthreads();

    int myb[8], myrank[8], myr[8], myc[8];
#pragma unroll
    for (int k = 0; k < 8; ++k) {
        const int i = t + k * BIN_T;
        if (i < nE) {
            myr[k] = row[e0 + i];
            myc[k] = col[e0 + i];
            myb[k] = myc[k] >> BKT_SHIFT;
            myrank[k] = atomicAdd(&bcnt[myb[k]], 1);
        }
    }
    __syncthreads();

    if (t < 256) sc[t] = (t < NB) ? bcnt[t] : 0;
    __syncthreads();
    for (int off = 1; off < 256; off <<= 1) {
        int v = 0;
        if (t < 256 && t >= off) v = sc[t - off];
        __syncthreads();
        if (t < 256) sc[t] += v;
        __syncthreads();
    }
    if (t < NB) {
        boff[t] = sc[t] - bcnt[t];
        if (bcnt[t] > 0) gbase[t] = atomicAdd(&gcur[t], bcnt[t]);
    }
    __syncthreads();

#pragma unroll
    for (int k = 0; k < 8; ++k) {
        const int i = t + k * BIN_T;
        if (i < nE)
            stage[boff[myb[k]] + myrank[k]] = make_uint2((unsigned)myr[k], (unsigned)myc[k]);
    }
    __syncthreads();

    for (int s = t; s < nE; s += BIN_T) {
        const uint2 p = stage[s];
        const int b = (int)(p.y >> BKT_SHIFT);
        pairs[(size_t)b * CAP + gbase[b] + (s - boff[b])] = p;
    }
}

// ---------------- bucket bases: exclusive scan of 196 bucket counts ----------

__global__ void k_bases(const int* __restrict__ gcur, int* __restrict__ bbase,
                        int* __restrict__ offsets) {
    __shared__ int sc[256];
    const int t = threadIdx.x;
    const int v = (t < NB) ? gcur[t] : 0;
    sc[t] = v;
    __syncthreads();
    for (int off = 1; off < 256; off <<= 1) {
        int u = (t >= off) ? sc[t - off] : 0;
        __syncthreads();
        sc[t] += u;
        __syncthreads();
    }
    if (t < NB) bbase[t] = sc[t] - v;
    if (t == 255) offsets[N_NODES] = sc[255];
}

// ---------------- phase 2: per-bucket node hist + scan + dense fill ----------

__global__ void k_fill2(const uint2* __restrict__ pairs, const int* __restrict__ gcur,
                        const int* __restrict__ bbase, int* __restrict__ offsets,
                        float* __restrict__ dinv, int* __restrict__ src) {
    __shared__ int ncnt[BKT_NODES];
    __shared__ int ncur[BKT_NODES];
    __shared__ int sc[256];
    const int b = blockIdx.x, t = threadIdx.x;
    const int base = b << BKT_SHIFT;
    const int nNodes = min(BKT_NODES, N_NODES - base);
    const int nE = gcur[b];
    const int gb = bbase[b];
    const uint2* bp = pairs + (size_t)b * CAP;

    for (int i = t; i < BKT_NODES; i += 256) ncnt[i] = 0;
    __syncthreads();
    for (int i = t; i < nE; i += 256) atomicAdd(&ncnt[(int)bp[i].y - base], 1);
    __syncthreads();

    const int c0 = ncnt[2 * t], c1 = ncnt[2 * t + 1];
    sc[t] = c0 + c1;
    __syncthreads();
    for (int off = 1; off < 256; off <<= 1) {
        int u = (t >= off) ? sc[t - off] : 0;
        __syncthreads();
        sc[t] += u;
        __syncthreads();
    }
    const int pre = sc[t] - (c0 + c1);
    const int o0 = gb + pre;
    const int o1 = o0 + c0;
    if (2 * t < nNodes) {
        offsets[base + 2 * t] = o0;
        dinv[base + 2 * t] = rsqrtf((float)c0 + 1.0f);
        ncur[2 * t] = o0;
    }
    if (2 * t + 1 < nNodes) {
        offsets[base + 2 * t + 1] = o1;
        dinv[base + 2 * t + 1] = rsqrtf((float)c1 + 1.0f);
        ncur[2 * t + 1] = o1;
    }
    __syncthreads();

    for (int i = t; i < nE; i += 256) {
        const uint2 p = bp[i];
        const int pos = atomicAdd(&ncur[(int)p.y - base], 1);
        src[pos] = (int)p.x;
    }
}

// ---------------- layer 1: y = bf16(dinv * (|x| @ W1)), tiled GEMM ----------
// 256 threads, tile = 128 nodes x 128 dims. W1 and transposed |x|-tile in LDS.
// Thread (tx,ty): dims {tx*4..+3} u {64+tx*4..+3}, nodes {ty*8..+7}.

__global__ __launch_bounds__(XW_T) void k_xw(const float* __restrict__ x,
                                             const float* __restrict__ W1,
                                             const float* __restrict__ dinv,
                                             unsigned short* __restrict__ y) {
    __shared__ float ws[D_IN * D_HID];   // [k][dim]  32 KB
    __shared__ float xs[D_IN * XW_NODES];  // [k][node] 32 KB
    const int t = threadIdx.x;
    const int n0 = blockIdx.x * XW_NODES;

    // stage W1 (coalesced float4 copy)
    {
        const float4* W4 = (const float4*)W1;
        float4* ws4 = (float4*)ws;
        for (int i = t; i < D_IN * D_HID / 4; i += XW_T) ws4[i] = W4[i];
    }
    // stage |x| transposed: thread covers node nl = t>>1, k-half h = t&1
    {
        const int nl = t >> 1;
        const int h = t & 1;
        const int n = n0 + nl;
        if (n < N_NODES) {
            const float4* xr = (const float4*)(x + (size_t)n * D_IN + h * 32);
#pragma unroll
            for (int q = 0; q < 8; ++q) {
                const float4 v = xr[q];
                const int k = h * 32 + q * 4;
                xs[(k + 0) * XW_NODES + nl] = fabsf(v.x);
                xs[(k + 1) * XW_NODES + nl] = fabsf(v.y);
                xs[(k + 2) * XW_NODES + nl] = fabsf(v.z);
                xs[(k + 3) * XW_NODES + nl] = fabsf(v.w);
            }
        } else {
#pragma unroll
            for (int q = 0; q < 8; ++q) {
                const int k = h * 32 + q * 4;
                xs[(k + 0) * XW_NODES + nl] = 0.0f;
                xs[(k + 1) * XW_NODES + nl] = 0.0f;
                xs[(k + 2) * XW_NODES + nl] = 0.0f;
                xs[(k + 3) * XW_NODES + nl] = 0.0f;
            }
        }
    }
    __syncthreads();

    const int tx = t & 15;
    const int ty = t >> 4;

    float acc0[8][4];
    float acc1[8][4];
#pragma unroll
    for (int i = 0; i < 8; ++i)
#pragma unroll
        for (int j = 0; j < 4; ++j) { acc0[i][j] = 0.0f; acc1[i][j] = 0.0f; }

    const float4* xs4 = (const float4*)xs;
    const float4* ws4 = (const float4*)ws;
#pragma unroll 4
    for (int k = 0; k < D_IN; ++k) {
        const float4 xa = xs4[k * 32 + ty * 2];
        const float4 xb = xs4[k * 32 + ty * 2 + 1];
        const float4 wa = ws4[k * 32 + tx];            // dims tx*4..+3
        const float4 wb = ws4[k * 32 + 16 + tx];       // dims 64+tx*4..+3
        const float xn[8] = {xa.x, xa.y, xa.z, xa.w, xb.x, xb.y, xb.z, xb.w};
#pragma unroll
        for (int i = 0; i < 8; ++i) {
            acc0[i][0] = fmaf(xn[i], wa.x, acc0[i][0]);
            acc0[i][1] = fmaf(xn[i], wa.y, acc0[i][1]);
            acc0[i][2] = fmaf(xn[i], wa.z, acc0[i][2]);
            acc0[i][3] = fmaf(xn[i], wa.w, acc0[i][3]);
            acc1[i][0] = fmaf(xn[i], wb.x, acc1[i][0]);
            acc1[i][1] = fmaf(xn[i], wb.y, acc1[i][1]);
            acc1[i][2] = fmaf(xn[i], wb.z, acc1[i][2]);
            acc1[i][3] = fmaf(xn[i], wb.w, acc1[i][3]);
        }
    }

#pragma unroll
    for (int i = 0; i < 8; ++i) {
        const int n = n0 + ty * 8 + i;
        if (n < N_NODES) {
            const float di = dinv[n];
            ushort4 o0, o1;
            o0.x = f2bf(di * acc0[i][0]);
            o0.y = f2bf(di * acc0[i][1]);
            o0.z = f2bf(di * acc0[i][2]);
            o0.w = f2bf(di * acc0[i][3]);
            o1.x = f2bf(di * acc1[i][0]);
            o1.y = f2bf(di * acc1[i][1]);
            o1.z = f2bf(di * acc1[i][2]);
            o1.w = f2bf(di * acc1[i][3]);
            *(ushort4*)(y + (size_t)n * D_HID + tx * 4) = o0;
            *(ushort4*)(y + (size_t)n * D_HID + 64 + tx * 4) = o1;
        }
    }
}

// ---------------- layer 1 aggregate: 4 edge-groups x 16 dim-lanes, uint4 loads --

#define ACC8(v)                                                 \
    do {                                                        \
        a0 += __uint_as_float((v).x << 16);                     \
        a1 += __uint_as_float((v).x & 0xFFFF0000u);             \
        a2 += __uint_as_float((v).y << 16);                     \
        a3 += __uint_as_float((v).y & 0xFFFF0000u);             \
        a4 += __uint_as_float((v).z << 16);                     \
        a5 += __uint_as_float((v).z & 0xFFFF0000u);             \
        a6 += __uint_as_float((v).w << 16);                     \
        a7 += __uint_as_float((v).w & 0xFFFF0000u);             \
    } while (0)

__global__ void k_agg(const int* __restrict__ offsets, const int* __restrict__ src,
                      const unsigned short* __restrict__ y, const float* __restrict__ dinv,
                      const float* __restrict__ b1, const float* __restrict__ W2,
                      float* __restrict__ z) {
    const int t = blockIdx.x * blockDim.x + threadIdx.x;
    const int node = t >> 6;  // one wave per node
    const int lane = t & 63;
    if (node >= N_NODES) return;
    const int eg = lane >> 4;  // edge group 0..3
    const int dc = lane & 15;  // dim chunk: dims 8*dc .. 8*dc+7

    float a0 = 0, a1 = 0, a2 = 0, a3 = 0, a4 = 0, a5 = 0, a6 = 0, a7 = 0;

    if (eg == 0) {  // self-loop term, counted once
        const uint4 v = ((const uint4*)(y + (size_t)node * D_HID))[dc];
        ACC8(v);
    }

    const int s0 = offsets[node], s1 = offsets[node + 1];
    int j = s0 + eg;
    for (; j + 4 < s1; j += 8) {  // 8 independent gathers in flight per wave
        const int r0 = src[j];
        const int r1 = src[j + 4];
        const uint4 v0 = ((const uint4*)(y + (size_t)r0 * D_HID))[dc];
        const uint4 v1 = ((const uint4*)(y + (size_t)r1 * D_HID))[dc];
        ACC8(v0);
        ACC8(v1);
    }
    if (j < s1) {
        const int r = src[j];
        const uint4 v = ((const uint4*)(y + (size_t)r * D_HID))[dc];
        ACC8(v);
    }

#pragma unroll
    for (int m = 16; m <= 32; m <<= 1) {
        a0 += __shfl_xor(a0, m, 64);
        a1 += __shfl_xor(a1, m, 64);
        a2 += __shfl_xor(a2, m, 64);
        a3 += __shfl_xor(a3, m, 64);
        a4 += __shfl_xor(a4, m, 64);
        a5 += __shfl_xor(a5, m, 64);
        a6 += __shfl_xor(a6, m, 64);
        a7 += __shfl_xor(a7, m, 64);
    }

    const float di = dinv[node];
    const float4 b1a = ((const float4*)(b1 + 8 * dc))[0];
    const float4 b1b = ((const float4*)(b1 + 8 * dc))[1];
    const float4 w2a = ((const float4*)(W2 + 8 * dc))[0];
    const float4 w2b = ((const float4*)(W2 + 8 * dc))[1];
    float sv;
    {
        float h;
        h = fmaxf(fmaf(di, a0, b1a.x), 0.0f); sv = h * w2a.x;
        h = fmaxf(fmaf(di, a1, b1a.y), 0.0f); sv = fmaf(h, w2a.y, sv);
        h = fmaxf(fmaf(di, a2, b1a.z), 0.0f); sv = fmaf(h, w2a.z, sv);
        h = fmaxf(fmaf(di, a3, b1a.w), 0.0f); sv = fmaf(h, w2a.w, sv);
        h = fmaxf(fmaf(di, a4, b1b.x), 0.0f); sv = fmaf(h, w2b.x, sv);
        h = fmaxf(fmaf(di, a5, b1b.y), 0.0f); sv = fmaf(h, w2b.y, sv);
        h = fmaxf(fmaf(di, a6, b1b.z), 0.0f); sv = fmaf(h, w2b.z, sv);
        h = fmaxf(fmaf(di, a7, b1b.w), 0.0f); sv = fmaf(h, w2b.w, sv);
    }
#pragma unroll
    for (int m = 1; m <= 8; m <<= 1) sv += __shfl_xor(sv, m, 64);
    if (lane == 0) z[node] = di * sv;
}

// ---------------- layer 2 aggregate + final ----------------

__global__ void k_out(const int* __restrict__ offsets, const int* __restrict__ src,
                      const float* __restrict__ z, const float* __restrict__ dinv,
                      const float* __restrict__ b2, float* __restrict__ out, int n) {
    const int i = blockIdx.x * blockDim.x + threadIdx.x;
    if (i >= n) return;
    float s = z[i];  // self-loop
    const int s0 = offsets[i], s1 = offsets[i + 1];
    for (int j = s0; j < s1; ++j) s += z[src[j]];
    float v = fmaf(dinv[i], s, b2[0]);
    v = fmaxf(v, 0.0f);
    out[i] = 1.0f / (1.0f + expf(-v));
}

extern "C" void kernel_launch(void* const* d_in, const int* in_sizes, int n_in,
                              void* d_out, int out_size, void* d_ws, size_t ws_size,
                              hipStream_t stream) {
    const float* x  = (const float*)d_in[0];
    const int* ei   = (const int*)d_in[1];
    const float* W1 = (const float*)d_in[2];
    const float* b1 = (const float*)d_in[3];
    const float* W2 = (const float*)d_in[4];
    const float* b2 = (const float*)d_in[5];
    float* out = (float*)d_out;

    const int* row = ei;
    const int* col = ei + N_EDGES;

    // workspace layout
    char* p = (char*)d_ws;
    float* dinv          = (float*)p;          p += sizeof(float) * N_NODES;
    unsigned short* y    = (unsigned short*)p; p += sizeof(unsigned short) * (size_t)N_NODES * D_HID;
    float* z             = (float*)p;          p += sizeof(float) * N_NODES;
    int* offsets         = (int*)p;            p += sizeof(int) * (N_NODES + 1);
    int* src             = (int*)p;            p += sizeof(int) * N_EDGES;
    int* gcur            = (int*)p;            p += sizeof(int) * NB;
    int* bbase           = (int*)p;            p += sizeof(int) * NB;
    p = (char*)(((size_t)p + 15) & ~(size_t)15);
    uint2* pairs         = (uint2*)p;          p += sizeof(uint2) * (size_t)NB * CAP;

    k_zero<<<1, 256, 0, stream>>>(gcur, NB);
    k_bin<<<(N_EDGES + CHUNK - 1) / CHUNK, BIN_T, 0, stream>>>(row, col, gcur, pairs);
    k_bases<<<1, 256, 0, stream>>>(gcur, bbase, offsets);
    k_fill2<<<NB, 256, 0, stream>>>(pairs, gcur, bbase, offsets, dinv, src);

    k_xw<<<XW_NBLK, XW_T, 0, stream>>>(x, W1, dinv, y);

    {
        const long long threads = (long long)N_NODES * 64;
        k_agg<<<(int)((threads + 255) / 256), 256, 0, stream>>>(offsets, src, y, dinv, b1, W2, z);
    }

    k_out<<<(N_NODES + 255) / 256, 256, 0, stream>>>(offsets, src, z, dinv, b2, out, N_NODES);
}

// Round 7
// 156.346 us; speedup vs baseline: 10.1088x; 1.0154x over previous
//
#include <hip/hip_runtime.h>
#include <math.h>

#define N_NODES 100000
#define N_EDGES 1600000
#define D_IN 64
#define D_HID 128

#define BKT_SHIFT 9
#define BKT_NODES 512
#define NB ((N_NODES + BKT_NODES - 1) / BKT_NODES)  // 196
#define CAP 16384                                    // per-bucket capacity (mean ~8163)
#define CHUNK 4096
#define BIN_T 512
#define FILL_T 512

#define XW_T 256
#define XW_NODES 128
#define XW_NBLK ((N_NODES + XW_NODES - 1) / XW_NODES)  // 782

// packed edge: bits 0..16 = row (src node), bits 17..25 = dst & 511
#define PACK(row, col) (((unsigned)((col) & (BKT_NODES - 1)) << 17) | (unsigned)(row))
#define P_ROW(u) ((int)((u) & 0x1FFFFu))
#define P_DST(u) ((int)(((u) >> 17) & 0x1FFu))

static __device__ __forceinline__ unsigned short f2bf(float f) {
    unsigned int u = __float_as_uint(f);
    u += 0x7FFFu + ((u >> 16) & 1u);  // round-to-nearest-even
    return (unsigned short)(u >> 16);
}

// ---------------- phase 1: LDS counting-sort edges into 196 col-buckets ------

__global__ __launch_bounds__(BIN_T) void k_bin(const int* __restrict__ row,
                                               const int* __restrict__ col,
                                               int* __restrict__ gcur,
                                               unsigned* __restrict__ pairs) {
    __shared__ int bcnt[NB];
    __shared__ int boff[NB];
    __shared__ int gbase[NB];
    __shared__ int sc[256];
    __shared__ unsigned stage[CHUNK];          // 16 KB
    __shared__ unsigned char bkt_of[CHUNK];    // 4 KB
    const int t = threadIdx.x;
    const int e0 = blockIdx.x * CHUNK;
    const int nE = min(CHUNK, N_EDGES - e0);

    for (int i = t; i < NB; i += BIN_T) bcnt[i] = 0;
    __syncthreads();

    int myb[8], myrank[8], myr[8], myc[8];
#pragma unroll
    for (int k = 0; k < 8; ++k) {
        const int i = t + k * BIN_T;
        if (i < nE) {
            myr[k] = row[e0 + i];
            myc[k] = col[e0 + i];
            myb[k] = myc[k] >> BKT_SHIFT;
            myrank[k] = atomicAdd(&bcnt[myb[k]], 1);
        }
    }
    __syncthreads();

    if (t < 256) sc[t] = (t < NB) ? bcnt[t] : 0;
    __syncthreads();
    for (int off = 1; off < 256; off <<= 1) {
        int v = 0;
        if (t < 256 && t >= off) v = sc[t - off];
        __syncthreads();
        if (t < 256) sc[t] += v;
        __syncthreads();
    }
    if (t < NB) {
        boff[t] = sc[t] - bcnt[t];
        if (bcnt[t] > 0) gbase[t] = atomicAdd(&gcur[t], bcnt[t]);
    }
    __syncthreads();

    // bucket lookup table for copy-out
    if (t < NB) {
        const int s = boff[t], e = s + bcnt[t];
        for (int i = s; i < e; ++i) bkt_of[i] = (unsigned char)t;
    }

    // stage into bucket-sorted order in LDS
#pragma unroll
    for (int k = 0; k < 8; ++k) {
        const int i = t + k * BIN_T;
        if (i < nE) stage[boff[myb[k]] + myrank[k]] = PACK(myr[k], myc[k]);
    }
    __syncthreads();

    // copy out: bucket-contiguous runs -> dense global writes
    for (int s = t; s < nE; s += BIN_T) {
        const int b = bkt_of[s];
        pairs[(size_t)b * CAP + gbase[b] + (s - boff[b])] = stage[s];
    }
}

// ---------------- phase 2: per-bucket hist + scan + dense fill (bases fused) --

__global__ __launch_bounds__(FILL_T) void k_fill2(const unsigned* __restrict__ pairs,
                                                  const int* __restrict__ gcur,
                                                  int* __restrict__ offsets,
                                                  float* __restrict__ dinv,
                                                  int* __restrict__ src) {
    __shared__ unsigned stage[CAP];      // 64 KB
    __shared__ int ncnt[BKT_NODES];
    __shared__ int ncur[BKT_NODES];
    __shared__ int sc[BKT_NODES];
    __shared__ int scb[256];
    const int b = blockIdx.x, t = threadIdx.x;
    const int base = b << BKT_SHIFT;
    const int nNodes = min(BKT_NODES, N_NODES - base);

    // redundant scan of the 196 bucket counts -> this block's global base
    if (t < 256) scb[t] = (t < NB) ? gcur[t] : 0;
    __syncthreads();
    for (int off = 1; off < 256; off <<= 1) {
        int v = 0;
        if (t < 256 && t >= off) v = scb[t - off];
        __syncthreads();
        if (t < 256) scb[t] += v;
        __syncthreads();
    }
    const int nE = gcur[b];
    const int gb = scb[b] - nE;  // exclusive prefix
    if (b == 0 && t == 0) offsets[N_NODES] = scb[NB - 1];

    // stage this bucket's packed edges in LDS (single global read)
    const unsigned* bp = pairs + (size_t)b * CAP;
    for (int i = t; i < nE; i += FILL_T) stage[i] = bp[i];
    for (int i = t; i < BKT_NODES; i += FILL_T) ncnt[i] = 0;
    __syncthreads();

    for (int i = t; i < nE; i += FILL_T) atomicAdd(&ncnt[P_DST(stage[i])], 1);
    __syncthreads();

    // scan 512 node counters with 512 threads
    const int c = ncnt[t];
    sc[t] = c;
    __syncthreads();
    for (int off = 1; off < BKT_NODES; off <<= 1) {
        int u = (t >= off) ? sc[t - off] : 0;
        __syncthreads();
        sc[t] += u;
        __syncthreads();
    }
    const int o = gb + sc[t] - c;  // exclusive
    if (t < nNodes) {
        offsets[base + t] = o;
        dinv[base + t] = rsqrtf((float)c + 1.0f);
    }
    ncur[t] = o;
    __syncthreads();

    for (int i = t; i < nE; i += FILL_T) {
        const unsigned u = stage[i];
        const int pos = atomicAdd(&ncur[P_DST(u)], 1);
        src[pos] = P_ROW(u);
    }
}

// ---------------- layer 1: y = bf16(dinv * (|x| @ W1)), tiled GEMM ----------

__global__ __launch_bounds__(XW_T) void k_xw(const float* __restrict__ x,
                                             const float* __restrict__ W1,
                                             const float* __restrict__ dinv,
                                             unsigned short* __restrict__ y) {
    __shared__ float ws[D_IN * D_HID];     // [k][dim]  32 KB
    __shared__ float xs[D_IN * XW_NODES];  // [k][node] 32 KB
    const int t = threadIdx.x;
    const int n0 = blockIdx.x * XW_NODES;

    {
        const float4* W4 = (const float4*)W1;
        float4* ws4 = (float4*)ws;
        for (int i = t; i < D_IN * D_HID / 4; i += XW_T) ws4[i] = W4[i];
    }
    {
        const int nl = t >> 1;
        const int h = t & 1;
        const int n = n0 + nl;
        if (n < N_NODES) {
            const float4* xr = (const float4*)(x + (size_t)n * D_IN + h * 32);
#pragma unroll
            for (int q = 0; q < 8; ++q) {
                const float4 v = xr[q];
                const int k = h * 32 + q * 4;
                xs[(k + 0) * XW_NODES + nl] = fabsf(v.x);
                xs[(k + 1) * XW_NODES + nl] = fabsf(v.y);
                xs[(k + 2) * XW_NODES + nl] = fabsf(v.z);
                xs[(k + 3) * XW_NODES + nl] = fabsf(v.w);
            }
        } else {
#pragma unroll
            for (int q = 0; q < 8; ++q) {
                const int k = h * 32 + q * 4;
                xs[(k + 0) * XW_NODES + nl] = 0.0f;
                xs[(k + 1) * XW_NODES + nl] = 0.0f;
                xs[(k + 2) * XW_NODES + nl] = 0.0f;
                xs[(k + 3) * XW_NODES + nl] = 0.0f;
            }
        }
    }
    __syncthreads();

    const int tx = t & 15;
    const int ty = t >> 4;

    float acc0[8][4];
    float acc1[8][4];
#pragma unroll
    for (int i = 0; i < 8; ++i)
#pragma unroll
        for (int j = 0; j < 4; ++j) { acc0[i][j] = 0.0f; acc1[i][j] = 0.0f; }

    const float4* xs4 = (const float4*)xs;
    const float4* ws4 = (const float4*)ws;
#pragma unroll 4
    for (int k = 0; k < D_IN; ++k) {
        const float4 xa = xs4[k * 32 + ty * 2];
        const float4 xb = xs4[k * 32 + ty * 2 + 1];
        const float4 wa = ws4[k * 32 + tx];
        const float4 wb = ws4[k * 32 + 16 + tx];
        const float xn[8] = {xa.x, xa.y, xa.z, xa.w, xb.x, xb.y, xb.z, xb.w};
#pragma unroll
        for (int i = 0; i < 8; ++i) {
            acc0[i][0] = fmaf(xn[i], wa.x, acc0[i][0]);
            acc0[i][1] = fmaf(xn[i], wa.y, acc0[i][1]);
            acc0[i][2] = fmaf(xn[i], wa.z, acc0[i][2]);
            acc0[i][3] = fmaf(xn[i], wa.w, acc0[i][3]);
            acc1[i][0] = fmaf(xn[i], wb.x, acc1[i][0]);
            acc1[i][1] = fmaf(xn[i], wb.y, acc1[i][1]);
            acc1[i][2] = fmaf(xn[i], wb.z, acc1[i][2]);
            acc1[i][3] = fmaf(xn[i], wb.w, acc1[i][3]);
        }
    }

#pragma unroll
    for (int i = 0; i < 8; ++i) {
        const int n = n0 + ty * 8 + i;
        if (n < N_NODES) {
            const float di = dinv[n];
            ushort4 o0, o1;
            o0.x = f2bf(di * acc0[i][0]);
            o0.y = f2bf(di * acc0[i][1]);
            o0.z = f2bf(di * acc0[i][2]);
            o0.w = f2bf(di * acc0[i][3]);
            o1.x = f2bf(di * acc1[i][0]);
            o1.y = f2bf(di * acc1[i][1]);
            o1.z = f2bf(di * acc1[i][2]);
            o1.w = f2bf(di * acc1[i][3]);
            *(ushort4*)(y + (size_t)n * D_HID + tx * 4) = o0;
            *(ushort4*)(y + (size_t)n * D_HID + 64 + tx * 4) = o1;
        }
    }
}

// ---------------- layer 1 aggregate: 4 edge-groups x 16 dim-lanes ----------

#define ACC8(v)                                                 \
    do {                                                        \
        a0 += __uint_as_float((v).x << 16);                     \
        a1 += __uint_as_float((v).x & 0xFFFF0000u);             \
        a2 += __uint_as_float((v).y << 16);                     \
        a3 += __uint_as_float((v).y & 0xFFFF0000u);             \
        a4 += __uint_as_float((v).z << 16);                     \
        a5 += __uint_as_float((v).z & 0xFFFF0000u);             \
        a6 += __uint_as_float((v).w << 16);                     \
        a7 += __uint_as_float((v).w & 0xFFFF0000u);             \
    } while (0)

__global__ void k_agg(const int* __restrict__ offsets, const int* __restrict__ src,
                      const unsigned short* __restrict__ y, const float* __restrict__ dinv,
                      const float* __restrict__ b1, const float* __restrict__ W2,
                      float* __restrict__ z) {
    const int t = blockIdx.x * blockDim.x + threadIdx.x;
    const int node = t >> 6;  // one wave per node
    const int lane = t & 63;
    if (node >= N_NODES) return;
    const int eg = lane >> 4;  // edge group 0..3
    const int dc = lane & 15;  // dim chunk: dims 8*dc .. 8*dc+7

    float a0 = 0, a1 = 0, a2 = 0, a3 = 0, a4 = 0, a5 = 0, a6 = 0, a7 = 0;

    if (eg == 0) {  // self-loop term, counted once
        const uint4 v = ((const uint4*)(y + (size_t)node * D_HID))[dc];
        ACC8(v);
    }

    const int s0 = offsets[node], s1 = offsets[node + 1];
    int j = s0 + eg;
    for (; j + 12 < s1; j += 16) {  // 16 independent gathers in flight per wave
        const int r0 = src[j];
        const int r1 = src[j + 4];
        const int r2 = src[j + 8];
        const int r3 = src[j + 12];
        const uint4 v0 = ((const uint4*)(y + (size_t)r0 * D_HID))[dc];
        const uint4 v1 = ((const uint4*)(y + (size_t)r1 * D_HID))[dc];
        const uint4 v2 = ((const uint4*)(y + (size_t)r2 * D_HID))[dc];
        const uint4 v3 = ((const uint4*)(y + (size_t)r3 * D_HID))[dc];
        ACC8(v0);
        ACC8(v1);
        ACC8(v2);
        ACC8(v3);
    }
    for (; j < s1; j += 4) {
        const int r = src[j];
        const uint4 v = ((const uint4*)(y + (size_t)r * D_HID))[dc];
        ACC8(v);
    }

#pragma unroll
    for (int m = 16; m <= 32; m <<= 1) {
        a0 += __shfl_xor(a0, m, 64);
        a1 += __shfl_xor(a1, m, 64);
        a2 += __shfl_xor(a2, m, 64);
        a3 += __shfl_xor(a3, m, 64);
        a4 += __shfl_xor(a4, m, 64);
        a5 += __shfl_xor(a5, m, 64);
        a6 += __shfl_xor(a6, m, 64);
        a7 += __shfl_xor(a7, m, 64);
    }

    const float di = dinv[node];
    const float4 b1a = ((const float4*)(b1 + 8 * dc))[0];
    const float4 b1b = ((const float4*)(b1 + 8 * dc))[1];
    const float4 w2a = ((const float4*)(W2 + 8 * dc))[0];
    const float4 w2b = ((const float4*)(W2 + 8 * dc))[1];
    float sv;
    {
        float h;
        h = fmaxf(fmaf(di, a0, b1a.x), 0.0f); sv = h * w2a.x;
        h = fmaxf(fmaf(di, a1, b1a.y), 0.0f); sv = fmaf(h, w2a.y, sv);
        h = fmaxf(fmaf(di, a2, b1a.z), 0.0f); sv = fmaf(h, w2a.z, sv);
        h = fmaxf(fmaf(di, a3, b1a.w), 0.0f); sv = fmaf(h, w2a.w, sv);
        h = fmaxf(fmaf(di, a4, b1b.x), 0.0f); sv = fmaf(h, w2b.x, sv);
        h = fmaxf(fmaf(di, a5, b1b.y), 0.0f); sv = fmaf(h, w2b.y, sv);
        h = fmaxf(fmaf(di, a6, b1b.z), 0.0f); sv = fmaf(h, w2b.z, sv);
        h = fmaxf(fmaf(di, a7, b1b.w), 0.0f); sv = fmaf(h, w2b.w, sv);
    }
#pragma unroll
    for (int m = 1; m <= 8; m <<= 1) sv += __shfl_xor(sv, m, 64);
    if (lane == 0) z[node] = di * sv;
}

// ---------------- layer 2 aggregate + final ----------------

__global__ void k_out(const int* __restrict__ offsets, const int* __restrict__ src,
                      const float* __restrict__ z, const float* __restrict__ dinv,
                      const float* __restrict__ b2, float* __restrict__ out, int n) {
    const int i = blockIdx.x * blockDim.x + threadIdx.x;
    if (i >= n) return;
    float s = z[i];  // self-loop
    const int s0 = offsets[i], s1 = offsets[i + 1];
    for (int j = s0; j < s1; ++j) s += z[src[j]];
    float v = fmaf(dinv[i], s, b2[0]);
    v = fmaxf(v, 0.0f);
    out[i] = 1.0f / (1.0f + expf(-v));
}

extern "C" void kernel_launch(void* const* d_in, const int* in_sizes, int n_in,
                              void* d_out, int out_size, void* d_ws, size_t ws_size,
                              hipStream_t stream) {
    const float* x  = (const float*)d_in[0];
    const int* ei   = (const int*)d_in[1];
    const float* W1 = (const float*)d_in[2];
    const float* b1 = (const float*)d_in[3];
    const float* W2 = (const float*)d_in[4];
    const float* b2 = (const float*)d_in[5];
    float* out = (float*)d_out;

    const int* row = ei;
    const int* col = ei + N_EDGES;

    // workspace layout
    char* p = (char*)d_ws;
    float* dinv          = (float*)p;          p += sizeof(float) * N_NODES;
    unsigned short* y    = (unsigned short*)p; p += sizeof(unsigned short) * (size_t)N_NODES * D_HID;
    float* z             = (float*)p;          p += sizeof(float) * N_NODES;
    int* offsets         = (int*)p;            p += sizeof(int) * (N_NODES + 1);
    int* src             = (int*)p;            p += sizeof(int) * N_EDGES;
    int* gcur            = (int*)p;            p += sizeof(int) * NB;
    p = (char*)(((size_t)p + 15) & ~(size_t)15);
    unsigned* pairs      = (unsigned*)p;       p += sizeof(unsigned) * (size_t)NB * CAP;

    hipMemsetAsync(gcur, 0, sizeof(int) * NB, stream);
    k_bin<<<(N_EDGES + CHUNK - 1) / CHUNK, BIN_T, 0, stream>>>(row, col, gcur, pairs);
    k_fill2<<<NB, FILL_T, 0, stream>>>(pairs, gcur, offsets, dinv, src);

    k_xw<<<XW_NBLK, XW_T, 0, stream>>>(x, W1, dinv, y);

    {
        const long long threads = (long long)N_NODES * 64;
        k_agg<<<(int)((threads + 255) / 256), 256, 0, stream>>>(offsets, src, y, dinv, b1, W2, z);
    }

    k_out<<<(N_NODES + 255) / 256, 256, 0, stream>>>(offsets, src, z, dinv, b2, out, N_NODES);
}

// Round 8
// 136.886 us; speedup vs baseline: 11.5458x; 1.1422x over previous
//
#include <hip/hip_runtime.h>
#include <math.h>

#define N_NODES 100000
#define N_EDGES 1600000
#define D_IN 64
#define D_HID 128

#define BKT_SHIFT 9
#define BKT_NODES 512
#define NB ((N_NODES + BKT_NODES - 1) / BKT_NODES)  // 196
#define CAP 16384                                    // per-bucket capacity (mean ~8163)
#define CHUNK 4096
#define BIN_T 512
#define FILL_T 512

#define XW_T 256
#define XW_NODES 128
#define XW_NBLK ((N_NODES + XW_NODES - 1) / XW_NODES)  // 782

// packed edge: bits 0..16 = row (src node), bits 17..25 = dst & 511
#define PACK(row, col) (((unsigned)((col) & (BKT_NODES - 1)) << 17) | (unsigned)(row))
#define P_ROW(u) ((int)((u) & 0x1FFFFu))
#define P_DST(u) ((int)(((u) >> 17) & 0x1FFu))

static __device__ __forceinline__ unsigned short f2bf(float f) {
    unsigned int u = __float_as_uint(f);
    u += 0x7FFFu + ((u >> 16) & 1u);  // round-to-nearest-even
    return (unsigned short)(u >> 16);
}

// ---------------- phase 1: LDS counting-sort edges into 196 col-buckets ------

__global__ __launch_bounds__(BIN_T) void k_bin(const int* __restrict__ row,
                                               const int* __restrict__ col,
                                               int* __restrict__ gcur,
                                               unsigned* __restrict__ pairs) {
    __shared__ int bcnt[NB];
    __shared__ int boff[NB];
    __shared__ int gbase[NB];
    __shared__ int sc[256];
    __shared__ unsigned stage[CHUNK];          // 16 KB
    __shared__ unsigned char bkt_of[CHUNK];    // 4 KB
    const int t = threadIdx.x;
    const int e0 = blockIdx.x * CHUNK;
    const int nE = min(CHUNK, N_EDGES - e0);

    for (int i = t; i < NB; i += BIN_T) bcnt[i] = 0;
    __syncthreads();

    int myb[8], myrank[8], myr[8], myc[8];
#pragma unroll
    for (int k = 0; k < 8; ++k) {
        const int i = t + k * BIN_T;
        if (i < nE) {
            myr[k] = row[e0 + i];
            myc[k] = col[e0 + i];
            myb[k] = myc[k] >> BKT_SHIFT;
            myrank[k] = atomicAdd(&bcnt[myb[k]], 1);
        }
    }
    __syncthreads();

    if (t < 256) sc[t] = (t < NB) ? bcnt[t] : 0;
    __syncthreads();
    for (int off = 1; off < 256; off <<= 1) {
        int v = 0;
        if (t < 256 && t >= off) v = sc[t - off];
        __syncthreads();
        if (t < 256) sc[t] += v;
        __syncthreads();
    }
    if (t < NB) {
        boff[t] = sc[t] - bcnt[t];
        if (bcnt[t] > 0) gbase[t] = atomicAdd(&gcur[t], bcnt[t]);
    }
    __syncthreads();

    if (t < NB) {
        const int s = boff[t], e = s + bcnt[t];
        for (int i = s; i < e; ++i) bkt_of[i] = (unsigned char)t;
    }

#pragma unroll
    for (int k = 0; k < 8; ++k) {
        const int i = t + k * BIN_T;
        if (i < nE) stage[boff[myb[k]] + myrank[k]] = PACK(myr[k], myc[k]);
    }
    __syncthreads();

    for (int s = t; s < nE; s += BIN_T) {
        const int b = bkt_of[s];
        pairs[(size_t)b * CAP + gbase[b] + (s - boff[b])] = stage[s];
    }
}

// ---------------- phase 2: per-bucket hist + scan + fill + xb = bf16(dinv*|x|) --

__global__ __launch_bounds__(FILL_T) void k_fill2(const unsigned* __restrict__ pairs,
                                                  const int* __restrict__ gcur,
                                                  const float* __restrict__ x,
                                                  int* __restrict__ offsets,
                                                  float* __restrict__ dinv,
                                                  int* __restrict__ src,
                                                  unsigned short* __restrict__ xb) {
    __shared__ unsigned stage[CAP];      // 64 KB
    __shared__ int ncnt[BKT_NODES];
    __shared__ int ncur[BKT_NODES];
    __shared__ int sc[BKT_NODES];
    __shared__ int scb[256];
    const int b = blockIdx.x, t = threadIdx.x;
    const int base = b << BKT_SHIFT;
    const int nNodes = min(BKT_NODES, N_NODES - base);

    // redundant scan of the 196 bucket counts -> this block's global base
    if (t < 256) scb[t] = (t < NB) ? gcur[t] : 0;
    __syncthreads();
    for (int off = 1; off < 256; off <<= 1) {
        int v = 0;
        if (t < 256 && t >= off) v = scb[t - off];
        __syncthreads();
        if (t < 256) scb[t] += v;
        __syncthreads();
    }
    const int nE = gcur[b];
    const int gb = scb[b] - nE;  // exclusive prefix
    if (b == 0 && t == 0) offsets[N_NODES] = scb[NB - 1];

    const unsigned* bp = pairs + (size_t)b * CAP;
    for (int i = t; i < nE; i += FILL_T) stage[i] = bp[i];
    for (int i = t; i < BKT_NODES; i += FILL_T) ncnt[i] = 0;
    __syncthreads();

    for (int i = t; i < nE; i += FILL_T) atomicAdd(&ncnt[P_DST(stage[i])], 1);
    __syncthreads();

    const int c = ncnt[t];
    sc[t] = c;
    __syncthreads();
    for (int off = 1; off < BKT_NODES; off <<= 1) {
        int u = (t >= off) ? sc[t - off] : 0;
        __syncthreads();
        sc[t] += u;
        __syncthreads();
    }
    const int o = gb + sc[t] - c;  // exclusive
    if (t < nNodes) {
        offsets[base + t] = o;
        dinv[base + t] = rsqrtf((float)c + 1.0f);
    }
    ncur[t] = o;
    __syncthreads();

    for (int i = t; i < nE; i += FILL_T) {
        const unsigned u = stage[i];
        const int pos = atomicAdd(&ncur[P_DST(u)], 1);
        src[pos] = P_ROW(u);
    }

    // xb = bf16(dinv * |x|) for this bucket's nodes (ncnt still holds degrees)
    for (int i = t; i < nNodes * (D_IN / 4); i += FILL_T) {
        const int nl = i >> 4;           // local node
        const int q = i & 15;            // float4 index within row
        const float di = rsqrtf((float)ncnt[nl] + 1.0f);
        const float4 v = ((const float4*)(x + (size_t)(base + nl) * D_IN))[q];
        ushort4 o4;
        o4.x = f2bf(di * fabsf(v.x));
        o4.y = f2bf(di * fabsf(v.y));
        o4.z = f2bf(di * fabsf(v.z));
        o4.w = f2bf(di * fabsf(v.w));
        *(ushort4*)(xb + (size_t)(base + nl) * D_IN + q * 4) = o4;
    }
}

// ---------------- aggregate in input space: agg64 = xb[node] + sum xb[src] ----
// 8 edge-groups x 8 dim-lanes; uint4 (8 bf16) per lane; f32 output.

#define ACC8(v)                                                 \
    do {                                                        \
        a0 += __uint_as_float((v).x << 16);                     \
        a1 += __uint_as_float((v).x & 0xFFFF0000u);             \
        a2 += __uint_as_float((v).y << 16);                     \
        a3 += __uint_as_float((v).y & 0xFFFF0000u);             \
        a4 += __uint_as_float((v).z << 16);                     \
        a5 += __uint_as_float((v).z & 0xFFFF0000u);             \
        a6 += __uint_as_float((v).w << 16);                     \
        a7 += __uint_as_float((v).w & 0xFFFF0000u);             \
    } while (0)

__global__ void k_agg64(const int* __restrict__ offsets, const int* __restrict__ src,
                        const unsigned short* __restrict__ xb,
                        float* __restrict__ agg64) {
    const int t = blockIdx.x * blockDim.x + threadIdx.x;
    const int node = t >> 6;  // one wave per node
    const int lane = t & 63;
    if (node >= N_NODES) return;
    const int eg = lane >> 3;  // edge group 0..7
    const int dc = lane & 7;   // dim chunk: dims 8*dc .. 8*dc+7

    float a0 = 0, a1 = 0, a2 = 0, a3 = 0, a4 = 0, a5 = 0, a6 = 0, a7 = 0;

    if (eg == 0) {  // self-loop term, counted once
        const uint4 v = ((const uint4*)(xb + (size_t)node * D_IN))[dc];
        ACC8(v);
    }

    const int s0 = offsets[node], s1 = offsets[node + 1];
    int j = s0 + eg;
    for (; j + 8 < s1; j += 16) {  // 16 independent gathers in flight per wave
        const int r0 = src[j];
        const int r1 = src[j + 8];
        const uint4 v0 = ((const uint4*)(xb + (size_t)r0 * D_IN))[dc];
        const uint4 v1 = ((const uint4*)(xb + (size_t)r1 * D_IN))[dc];
        ACC8(v0);
        ACC8(v1);
    }
    if (j < s1) {
        const int r = src[j];
        const uint4 v = ((const uint4*)(xb + (size_t)r * D_IN))[dc];
        ACC8(v);
    }

    // reduce across the 8 edge groups (lane bits 3,4,5)
#pragma unroll
    for (int m = 8; m <= 32; m <<= 1) {
        a0 += __shfl_xor(a0, m, 64);
        a1 += __shfl_xor(a1, m, 64);
        a2 += __shfl_xor(a2, m, 64);
        a3 += __shfl_xor(a3, m, 64);
        a4 += __shfl_xor(a4, m, 64);
        a5 += __shfl_xor(a5, m, 64);
        a6 += __shfl_xor(a6, m, 64);
        a7 += __shfl_xor(a7, m, 64);
    }

    if (eg == 0) {  // lanes 0..7 write the 64-f32 row
        float* dst = agg64 + (size_t)node * D_IN + dc * 8;
        float4 w0 = {a0, a1, a2, a3};
        float4 w1 = {a4, a5, a6, a7};
        ((float4*)dst)[0] = w0;
        ((float4*)dst)[1] = w1;
    }
}

// ---------------- fused GEMM: g = agg64 @ W1; h=relu(di*g+b1); z=di*(h.W2) ----
// 256 threads, tile = 128 nodes x 128 dims; thread (tx,ty): dims {tx*4, 64+tx*4},
// nodes {ty*8..+7}. Epilogue reduces h.W2 across the 16 tx lanes (lane bits 0-3).

__global__ __launch_bounds__(XW_T) void k_gemm(const float* __restrict__ agg64,
                                               const float* __restrict__ W1,
                                               const float* __restrict__ dinv,
                                               const float* __restrict__ b1,
                                               const float* __restrict__ W2,
                                               float* __restrict__ z) {
    __shared__ float ws[D_IN * D_HID];     // [k][dim]  32 KB
    __shared__ float xs[D_IN * XW_NODES];  // [k][node] 32 KB
    const int t = threadIdx.x;
    const int n0 = blockIdx.x * XW_NODES;

    {
        const float4* W4 = (const float4*)W1;
        float4* ws4 = (float4*)ws;
        for (int i = t; i < D_IN * D_HID / 4; i += XW_T) ws4[i] = W4[i];
    }
    {
        const int nl = t >> 1;
        const int h = t & 1;
        const int n = n0 + nl;
        if (n < N_NODES) {
            const float4* xr = (const float4*)(agg64 + (size_t)n * D_IN + h * 32);
#pragma unroll
            for (int q = 0; q < 8; ++q) {
                const float4 v = xr[q];
                const int k = h * 32 + q * 4;
                xs[(k + 0) * XW_NODES + nl] = v.x;
                xs[(k + 1) * XW_NODES + nl] = v.y;
                xs[(k + 2) * XW_NODES + nl] = v.z;
                xs[(k + 3) * XW_NODES + nl] = v.w;
            }
        } else {
#pragma unroll
            for (int q = 0; q < 8; ++q) {
                const int k = h * 32 + q * 4;
                xs[(k + 0) * XW_NODES + nl] = 0.0f;
                xs[(k + 1) * XW_NODES + nl] = 0.0f;
                xs[(k + 2) * XW_NODES + nl] = 0.0f;
                xs[(k + 3) * XW_NODES + nl] = 0.0f;
            }
        }
    }
    __syncthreads();

    const int tx = t & 15;
    const int ty = t >> 4;

    float acc0[8][4];
    float acc1[8][4];
#pragma unroll
    for (int i = 0; i < 8; ++i)
#pragma unroll
        for (int j = 0; j < 4; ++j) { acc0[i][j] = 0.0f; acc1[i][j] = 0.0f; }

    const float4* xs4 = (const float4*)xs;
    const float4* ws4 = (const float4*)ws;
#pragma unroll 4
    for (int k = 0; k < D_IN; ++k) {
        const float4 xa = xs4[k * 32 + ty * 2];
        const float4 xb_ = xs4[k * 32 + ty * 2 + 1];
        const float4 wa = ws4[k * 32 + tx];
        const float4 wb = ws4[k * 32 + 16 + tx];
        const float xn[8] = {xa.x, xa.y, xa.z, xa.w, xb_.x, xb_.y, xb_.z, xb_.w};
#pragma unroll
        for (int i = 0; i < 8; ++i) {
            acc0[i][0] = fmaf(xn[i], wa.x, acc0[i][0]);
            acc0[i][1] = fmaf(xn[i], wa.y, acc0[i][1]);
            acc0[i][2] = fmaf(xn[i], wa.z, acc0[i][2]);
            acc0[i][3] = fmaf(xn[i], wa.w, acc0[i][3]);
            acc1[i][0] = fmaf(xn[i], wb.x, acc1[i][0]);
            acc1[i][1] = fmaf(xn[i], wb.y, acc1[i][1]);
            acc1[i][2] = fmaf(xn[i], wb.z, acc1[i][2]);
            acc1[i][3] = fmaf(xn[i], wb.w, acc1[i][3]);
        }
    }

    // epilogue: h = relu(di*g + b1); partial = h . W2 over this thread's 8 dims;
    // butterfly over tx (lane bits 0-3); tx==0 writes z.
    const float4 b1a = ((const float4*)(b1 + 4 * tx))[0];
    const float4 b1b = ((const float4*)(b1 + 64 + 4 * tx))[0];
    const float4 w2a = ((const float4*)(W2 + 4 * tx))[0];
    const float4 w2b = ((const float4*)(W2 + 64 + 4 * tx))[0];
#pragma unroll
    for (int i = 0; i < 8; ++i) {
        const int n = n0 + ty * 8 + i;
        if (n >= N_NODES) continue;
        const float di = dinv[n];
        float h, sv;
        h = fmaxf(fmaf(di, acc0[i][0], b1a.x), 0.0f); sv = h * w2a.x;
        h = fmaxf(fmaf(di, acc0[i][1], b1a.y), 0.0f); sv = fmaf(h, w2a.y, sv);
        h = fmaxf(fmaf(di, acc0[i][2], b1a.z), 0.0f); sv = fmaf(h, w2a.z, sv);
        h = fmaxf(fmaf(di, acc0[i][3], b1a.w), 0.0f); sv = fmaf(h, w2a.w, sv);
        h = fmaxf(fmaf(di, acc1[i][0], b1b.x), 0.0f); sv = fmaf(h, w2b.x, sv);
        h = fmaxf(fmaf(di, acc1[i][1], b1b.y), 0.0f); sv = fmaf(h, w2b.y, sv);
        h = fmaxf(fmaf(di, acc1[i][2], b1b.z), 0.0f); sv = fmaf(h, w2b.z, sv);
        h = fmaxf(fmaf(di, acc1[i][3], b1b.w), 0.0f); sv = fmaf(h, w2b.w, sv);
#pragma unroll
        for (int m = 1; m <= 8; m <<= 1) sv += __shfl_xor(sv, m, 64);
        if (tx == 0) z[n] = di * sv;
    }
}

// ---------------- layer 2 aggregate + final ----------------

__global__ void k_out(const int* __restrict__ offsets, const int* __restrict__ src,
                      const float* __restrict__ z, const float* __restrict__ dinv,
                      const float* __restrict__ b2, float* __restrict__ out, int n) {
    const int i = blockIdx.x * blockDim.x + threadIdx.x;
    if (i >= n) return;
    float s = z[i];  // self-loop
    const int s0 = offsets[i], s1 = offsets[i + 1];
    int j = s0;
    for (; j + 3 < s1; j += 4)
        s += z[src[j]] + z[src[j + 1]] + z[src[j + 2]] + z[src[j + 3]];
    for (; j < s1; ++j) s += z[src[j]];
    float v = fmaf(dinv[i], s, b2[0]);
    v = fmaxf(v, 0.0f);
    out[i] = 1.0f / (1.0f + expf(-v));
}

extern "C" void kernel_launch(void* const* d_in, const int* in_sizes, int n_in,
                              void* d_out, int out_size, void* d_ws, size_t ws_size,
                              hipStream_t stream) {
    const float* x  = (const float*)d_in[0];
    const int* ei   = (const int*)d_in[1];
    const float* W1 = (const float*)d_in[2];
    const float* b1 = (const float*)d_in[3];
    const float* W2 = (const float*)d_in[4];
    const float* b2 = (const float*)d_in[5];
    float* out = (float*)d_out;

    const int* row = ei;
    const int* col = ei + N_EDGES;

    // workspace layout
    char* p = (char*)d_ws;
    float* dinv          = (float*)p;          p += sizeof(float) * N_NODES;
    unsigned short* xb   = (unsigned short*)p; p += sizeof(unsigned short) * (size_t)N_NODES * D_IN;
    float* agg64         = (float*)p;          p += sizeof(float) * (size_t)N_NODES * D_IN;
    float* z             = (float*)p;          p += sizeof(float) * N_NODES;
    int* offsets         = (int*)p;            p += sizeof(int) * (N_NODES + 1);
    int* src             = (int*)p;            p += sizeof(int) * N_EDGES;
    int* gcur            = (int*)p;            p += sizeof(int) * NB;
    p = (char*)(((size_t)p + 15) & ~(size_t)15);
    unsigned* pairs      = (unsigned*)p;       p += sizeof(unsigned) * (size_t)NB * CAP;

    hipMemsetAsync(gcur, 0, sizeof(int) * NB, stream);
    k_bin<<<(N_EDGES + CHUNK - 1) / CHUNK, BIN_T, 0, stream>>>(row, col, gcur, pairs);
    k_fill2<<<NB, FILL_T, 0, stream>>>(pairs, gcur, x, offsets, dinv, src, xb);

    {
        const long long threads = (long long)N_NODES * 64;
        k_agg64<<<(int)((threads + 255) / 256), 256, 0, stream>>>(offsets, src, xb, agg64);
    }

    k_gemm<<<XW_NBLK, XW_T, 0, stream>>>(agg64, W1, dinv, b1, W2, z);

    k_out<<<(N_NODES + 255) / 256, 256, 0, stream>>>(offsets, src, z, dinv, b2, out, N_NODES);
}

// Round 9
// 132.116 us; speedup vs baseline: 11.9627x; 1.0361x over previous
//
#include <hip/hip_runtime.h>
#include <math.h>

#define N_NODES 100000
#define N_EDGES 1600000
#define D_IN 64
#define D_HID 128

#define BKT_SHIFT 9
#define BKT_NODES 512
#define NB ((N_NODES + BKT_NODES - 1) / BKT_NODES)  // 196
#define CAP 16384                                    // per-bucket capacity (mean ~8163)
#define CHUNK 8192
#define BIN_T 1024
#define FILL_T 1024

#define XW_T 256
#define XW_NODES 128
#define XW_NBLK ((N_NODES + XW_NODES - 1) / XW_NODES)  // 782

// packed edge: bits 0..16 = row (src node), bits 17..25 = dst & 511
#define PACK(row, col) (((unsigned)((col) & (BKT_NODES - 1)) << 17) | (unsigned)(row))
#define P_ROW(u) ((int)((u) & 0x1FFFFu))
#define P_DST(u) ((int)(((u) >> 17) & 0x1FFu))

static __device__ __forceinline__ unsigned short f2bf(float f) {
    unsigned int u = __float_as_uint(f);
    u += 0x7FFFu + ((u >> 16) & 1u);  // round-to-nearest-even
    return (unsigned short)(u >> 16);
}

// ---------------- phase 1: LDS counting-sort edges into 196 col-buckets ------

__global__ __launch_bounds__(BIN_T) void k_bin(const int* __restrict__ row,
                                               const int* __restrict__ col,
                                               int* __restrict__ gcur,
                                               unsigned* __restrict__ pairs) {
    __shared__ int bcnt[NB];
    __shared__ int boff[NB];
    __shared__ int gbase[NB];
    __shared__ int sc[256];
    __shared__ unsigned stage[CHUNK];          // 32 KB
    __shared__ unsigned char bkt_of[CHUNK];    // 8 KB
    const int t = threadIdx.x;
    const int e0 = blockIdx.x * CHUNK;
    const int nE = min(CHUNK, N_EDGES - e0);

    for (int i = t; i < NB; i += BIN_T) bcnt[i] = 0;
    __syncthreads();

    int myb[8], myrank[8], myr[8];
#pragma unroll
    for (int k = 0; k < 8; ++k) {
        const int i = t + k * BIN_T;
        if (i < nE) {
            myr[k] = row[e0 + i];
            const int c = col[e0 + i];
            myb[k] = c >> BKT_SHIFT;
            myrank[k] = atomicAdd(&bcnt[myb[k]], 1);
            myr[k] = PACK(myr[k], c);
        }
    }
    __syncthreads();

    if (t < 256) sc[t] = (t < NB) ? bcnt[t] : 0;
    __syncthreads();
    for (int off = 1; off < 256; off <<= 1) {
        int v = 0;
        if (t < 256 && t >= off) v = sc[t - off];
        __syncthreads();
        if (t < 256) sc[t] += v;
        __syncthreads();
    }
    if (t < NB) {
        boff[t] = sc[t] - bcnt[t];
        if (bcnt[t] > 0) gbase[t] = atomicAdd(&gcur[t], bcnt[t]);
    }
    __syncthreads();

    if (t < NB) {
        const int s = boff[t], e = s + bcnt[t];
        for (int i = s; i < e; ++i) bkt_of[i] = (unsigned char)t;
    }

#pragma unroll
    for (int k = 0; k < 8; ++k) {
        const int i = t + k * BIN_T;
        if (i < nE) stage[boff[myb[k]] + myrank[k]] = (unsigned)myr[k];
    }
    __syncthreads();

    for (int s = t; s < nE; s += BIN_T) {
        const int b = bkt_of[s];
        pairs[(size_t)b * CAP + gbase[b] + (s - boff[b])] = stage[s];
    }
}

// ---------------- phase 2: per-bucket hist + scan + dense fill ----------------

__global__ __launch_bounds__(FILL_T) void k_fill2(const unsigned* __restrict__ pairs,
                                                  const int* __restrict__ gcur,
                                                  int* __restrict__ offsets,
                                                  float* __restrict__ dinv,
                                                  int* __restrict__ src) {
    __shared__ unsigned stage[CAP];      // 64 KB
    __shared__ int ncnt[BKT_NODES];
    __shared__ int ncur[BKT_NODES];
    __shared__ int sc[BKT_NODES];
    __shared__ int scb[256];
    const int b = blockIdx.x, t = threadIdx.x;
    const int base = b << BKT_SHIFT;
    const int nNodes = min(BKT_NODES, N_NODES - base);

    // redundant scan of the 196 bucket counts -> this block's global base
    if (t < 256) scb[t] = (t < NB) ? gcur[t] : 0;
    __syncthreads();
    for (int off = 1; off < 256; off <<= 1) {
        int v = 0;
        if (t < 256 && t >= off) v = scb[t - off];
        __syncthreads();
        if (t < 256) scb[t] += v;
        __syncthreads();
    }
    const int nE = gcur[b];
    const int gb = scb[b] - nE;  // exclusive prefix
    if (b == 0 && t == 0) offsets[N_NODES] = scb[NB - 1];

    const unsigned* bp = pairs + (size_t)b * CAP;
    for (int i = t; i < nE; i += FILL_T) stage[i] = bp[i];
    for (int i = t; i < BKT_NODES; i += FILL_T) ncnt[i] = 0;
    __syncthreads();

    for (int i = t; i < nE; i += FILL_T) atomicAdd(&ncnt[P_DST(stage[i])], 1);
    __syncthreads();

    const int c = (t < BKT_NODES) ? ncnt[t] : 0;
    if (t < BKT_NODES) sc[t] = c;
    __syncthreads();
    for (int off = 1; off < BKT_NODES; off <<= 1) {
        int u = 0;
        if (t < BKT_NODES && t >= off) u = sc[t - off];
        __syncthreads();
        if (t < BKT_NODES) sc[t] += u;
        __syncthreads();
    }
    if (t < BKT_NODES) {
        const int o = gb + sc[t] - c;  // exclusive
        if (t < nNodes) {
            offsets[base + t] = o;
            dinv[base + t] = rsqrtf((float)c + 1.0f);
        }
        ncur[t] = o;
    }
    __syncthreads();

    for (int i = t; i < nE; i += FILL_T) {
        const unsigned u = stage[i];
        const int pos = atomicAdd(&ncur[P_DST(u)], 1);
        src[pos] = P_ROW(u);
    }
}

// ---------------- xb = bf16(dinv * |x|), streaming elementwise ----------------

__global__ void k_xb(const float* __restrict__ x, const float* __restrict__ dinv,
                     unsigned short* __restrict__ xb) {
    const int total = N_NODES * (D_IN / 4);
    for (int i = blockIdx.x * blockDim.x + threadIdx.x; i < total;
         i += gridDim.x * blockDim.x) {
        const int n = i >> 4;
        const int q = i & 15;
        const float di = dinv[n];
        const float4 v = ((const float4*)(x + (size_t)n * D_IN))[q];
        ushort4 o4;
        o4.x = f2bf(di * fabsf(v.x));
        o4.y = f2bf(di * fabsf(v.y));
        o4.z = f2bf(di * fabsf(v.z));
        o4.w = f2bf(di * fabsf(v.w));
        *(ushort4*)(xb + (size_t)n * D_IN + q * 4) = o4;
    }
}

// ---------------- aggregate in input space: aggb = bf16(xb[node] + sum xb[src]) --
// 8 edge-groups x 8 dim-lanes; uint4 (8 bf16) per lane; bf16 output.

#define ACC8(v)                                                 \
    do {                                                        \
        a0 += __uint_as_float((v).x << 16);                     \
        a1 += __uint_as_float((v).x & 0xFFFF0000u);             \
        a2 += __uint_as_float((v).y << 16);                     \
        a3 += __uint_as_float((v).y & 0xFFFF0000u);             \
        a4 += __uint_as_float((v).z << 16);                     \
        a5 += __uint_as_float((v).z & 0xFFFF0000u);             \
        a6 += __uint_as_float((v).w << 16);                     \
        a7 += __uint_as_float((v).w & 0xFFFF0000u);             \
    } while (0)

__global__ void k_agg64(const int* __restrict__ offsets, const int* __restrict__ src,
                        const unsigned short* __restrict__ xb,
                        unsigned short* __restrict__ aggb) {
    const int t = blockIdx.x * blockDim.x + threadIdx.x;
    const int node = t >> 6;  // one wave per node
    const int lane = t & 63;
    if (node >= N_NODES) return;
    const int eg = lane >> 3;  // edge group 0..7
    const int dc = lane & 7;   // dim chunk: dims 8*dc .. 8*dc+7

    float a0 = 0, a1 = 0, a2 = 0, a3 = 0, a4 = 0, a5 = 0, a6 = 0, a7 = 0;

    if (eg == 0) {  // self-loop term, counted once
        const uint4 v = ((const uint4*)(xb + (size_t)node * D_IN))[dc];
        ACC8(v);
    }

    const int s0 = offsets[node], s1 = offsets[node + 1];
    int j = s0 + eg;
    for (; j + 8 < s1; j += 16) {  // 16 independent gathers in flight per wave
        const int r0 = src[j];
        const int r1 = src[j + 8];
        const uint4 v0 = ((const uint4*)(xb + (size_t)r0 * D_IN))[dc];
        const uint4 v1 = ((const uint4*)(xb + (size_t)r1 * D_IN))[dc];
        ACC8(v0);
        ACC8(v1);
    }
    if (j < s1) {
        const int r = src[j];
        const uint4 v = ((const uint4*)(xb + (size_t)r * D_IN))[dc];
        ACC8(v);
    }

    // reduce across the 8 edge groups (lane bits 3,4,5)
#pragma unroll
    for (int m = 8; m <= 32; m <<= 1) {
        a0 += __shfl_xor(a0, m, 64);
        a1 += __shfl_xor(a1, m, 64);
        a2 += __shfl_xor(a2, m, 64);
        a3 += __shfl_xor(a3, m, 64);
        a4 += __shfl_xor(a4, m, 64);
        a5 += __shfl_xor(a5, m, 64);
        a6 += __shfl_xor(a6, m, 64);
        a7 += __shfl_xor(a7, m, 64);
    }

    if (eg == 0) {  // lanes 0..7 write the 64-bf16 row (128 B contiguous)
        uint4 w;
        w.x = (unsigned)f2bf(a0) | ((unsigned)f2bf(a1) << 16);
        w.y = (unsigned)f2bf(a2) | ((unsigned)f2bf(a3) << 16);
        w.z = (unsigned)f2bf(a4) | ((unsigned)f2bf(a5) << 16);
        w.w = (unsigned)f2bf(a6) | ((unsigned)f2bf(a7) << 16);
        *(uint4*)(aggb + (size_t)node * D_IN + dc * 8) = w;
    }
}

// ---------------- fused GEMM: g = aggb @ W1; h=relu(di*g+b1); z=di*(h.W2) ----

__global__ __launch_bounds__(XW_T) void k_gemm(const unsigned short* __restrict__ aggb,
                                               const float* __restrict__ W1,
                                               const float* __restrict__ dinv,
                                               const float* __restrict__ b1,
                                               const float* __restrict__ W2,
                                               float* __restrict__ z) {
    __shared__ float ws[D_IN * D_HID];     // [k][dim]  32 KB
    __shared__ float xs[D_IN * XW_NODES];  // [k][node] 32 KB
    const int t = threadIdx.x;
    const int n0 = blockIdx.x * XW_NODES;

    {
        const float4* W4 = (const float4*)W1;
        float4* ws4 = (float4*)ws;
        for (int i = t; i < D_IN * D_HID / 4; i += XW_T) ws4[i] = W4[i];
    }
    {
        const int nl = t >> 1;
        const int h = t & 1;
        const int n = n0 + nl;
        if (n < N_NODES) {
            const uint4* xr = (const uint4*)(aggb + (size_t)n * D_IN + h * 32);
#pragma unroll
            for (int q = 0; q < 4; ++q) {
                const uint4 v = xr[q];
                const int k = h * 32 + q * 8;
                xs[(k + 0) * XW_NODES + nl] = __uint_as_float(v.x << 16);
                xs[(k + 1) * XW_NODES + nl] = __uint_as_float(v.x & 0xFFFF0000u);
                xs[(k + 2) * XW_NODES + nl] = __uint_as_float(v.y << 16);
                xs[(k + 3) * XW_NODES + nl] = __uint_as_float(v.y & 0xFFFF0000u);
                xs[(k + 4) * XW_NODES + nl] = __uint_as_float(v.z << 16);
                xs[(k + 5) * XW_NODES + nl] = __uint_as_float(v.z & 0xFFFF0000u);
                xs[(k + 6) * XW_NODES + nl] = __uint_as_float(v.w << 16);
                xs[(k + 7) * XW_NODES + nl] = __uint_as_float(v.w & 0xFFFF0000u);
            }
        } else {
#pragma unroll
            for (int q = 0; q < 8; ++q) {
                const int k = h * 32 + q * 4;
                xs[(k + 0) * XW_NODES + nl] = 0.0f;
                xs[(k + 1) * XW_NODES + nl] = 0.0f;
                xs[(k + 2) * XW_NODES + nl] = 0.0f;
                xs[(k + 3) * XW_NODES + nl] = 0.0f;
            }
        }
    }
    __syncthreads();

    const int tx = t & 15;
    const int ty = t >> 4;

    float acc0[8][4];
    float acc1[8][4];
#pragma unroll
    for (int i = 0; i < 8; ++i)
#pragma unroll
        for (int j = 0; j < 4; ++j) { acc0[i][j] = 0.0f; acc1[i][j] = 0.0f; }

    const float4* xs4 = (const float4*)xs;
    const float4* ws4 = (const float4*)ws;
#pragma unroll 4
    for (int k = 0; k < D_IN; ++k) {
        const float4 xa = xs4[k * 32 + ty * 2];
        const float4 xb_ = xs4[k * 32 + ty * 2 + 1];
        const float4 wa = ws4[k * 32 + tx];
        const float4 wb = ws4[k * 32 + 16 + tx];
        const float xn[8] = {xa.x, xa.y, xa.z, xa.w, xb_.x, xb_.y, xb_.z, xb_.w};
#pragma unroll
        for (int i = 0; i < 8; ++i) {
            acc0[i][0] = fmaf(xn[i], wa.x, acc0[i][0]);
            acc0[i][1] = fmaf(xn[i], wa.y, acc0[i][1]);
            acc0[i][2] = fmaf(xn[i], wa.z, acc0[i][2]);
            acc0[i][3] = fmaf(xn[i], wa.w, acc0[i][3]);
            acc1[i][0] = fmaf(xn[i], wb.x, acc1[i][0]);
            acc1[i][1] = fmaf(xn[i], wb.y, acc1[i][1]);
            acc1[i][2] = fmaf(xn[i], wb.z, acc1[i][2]);
            acc1[i][3] = fmaf(xn[i], wb.w, acc1[i][3]);
        }
    }

    // epilogue: h = relu(di*g + b1); partial = h . W2; butterfly over tx lanes
    const float4 b1a = ((const float4*)(b1 + 4 * tx))[0];
    const float4 b1b = ((const float4*)(b1 + 64 + 4 * tx))[0];
    const float4 w2a = ((const float4*)(W2 + 4 * tx))[0];
    const float4 w2b = ((const float4*)(W2 + 64 + 4 * tx))[0];
#pragma unroll
    for (int i = 0; i < 8; ++i) {
        const int n = n0 + ty * 8 + i;
        if (n >= N_NODES) continue;
        const float di = dinv[n];
        float h, sv;
        h = fmaxf(fmaf(di, acc0[i][0], b1a.x), 0.0f); sv = h * w2a.x;
        h = fmaxf(fmaf(di, acc0[i][1], b1a.y), 0.0f); sv = fmaf(h, w2a.y, sv);
        h = fmaxf(fmaf(di, acc0[i][2], b1a.z), 0.0f); sv = fmaf(h, w2a.z, sv);
        h = fmaxf(fmaf(di, acc0[i][3], b1a.w), 0.0f); sv = fmaf(h, w2a.w, sv);
        h = fmaxf(fmaf(di, acc1[i][0], b1b.x), 0.0f); sv = fmaf(h, w2b.x, sv);
        h = fmaxf(fmaf(di, acc1[i][1], b1b.y), 0.0f); sv = fmaf(h, w2b.y, sv);
        h = fmaxf(fmaf(di, acc1[i][2], b1b.z), 0.0f); sv = fmaf(h, w2b.z, sv);
        h = fmaxf(fmaf(di, acc1[i][3], b1b.w), 0.0f); sv = fmaf(h, w2b.w, sv);
#pragma unroll
        for (int m = 1; m <= 8; m <<= 1) sv += __shfl_xor(sv, m, 64);
        if (tx == 0) z[n] = di * sv;
    }
}

// ---------------- layer 2 aggregate + final ----------------

__global__ void k_out(const int* __restrict__ offsets, const int* __restrict__ src,
                      const float* __restrict__ z, const float* __restrict__ dinv,
                      const float* __restrict__ b2, float* __restrict__ out, int n) {
    const int i = blockIdx.x * blockDim.x + threadIdx.x;
    if (i >= n) return;
    float s = z[i];  // self-loop
    const int s0 = offsets[i], s1 = offsets[i + 1];
    int j = s0;
    for (; j + 3 < s1; j += 4)
        s += z[src[j]] + z[src[j + 1]] + z[src[j + 2]] + z[src[j + 3]];
    for (; j < s1; ++j) s += z[src[j]];
    float v = fmaf(dinv[i], s, b2[0]);
    v = fmaxf(v, 0.0f);
    out[i] = 1.0f / (1.0f + expf(-v));
}

extern "C" void kernel_launch(void* const* d_in, const int* in_sizes, int n_in,
                              void* d_out, int out_size, void* d_ws, size_t ws_size,
                              hipStream_t stream) {
    const float* x  = (const float*)d_in[0];
    const int* ei   = (const int*)d_in[1];
    const float* W1 = (const float*)d_in[2];
    const float* b1 = (const float*)d_in[3];
    const float* W2 = (const float*)d_in[4];
    const float* b2 = (const float*)d_in[5];
    float* out = (float*)d_out;

    const int* row = ei;
    const int* col = ei + N_EDGES;

    // workspace layout
    char* p = (char*)d_ws;
    float* dinv          = (float*)p;          p += sizeof(float) * N_NODES;
    unsigned short* xb   = (unsigned short*)p; p += sizeof(unsigned short) * (size_t)N_NODES * D_IN;
    unsigned short* aggb = (unsigned short*)p; p += sizeof(unsigned short) * (size_t)N_NODES * D_IN;
    float* z             = (float*)p;          p += sizeof(float) * N_NODES;
    int* offsets         = (int*)p;            p += sizeof(int) * (N_NODES + 1);
    int* src             = (int*)p;            p += sizeof(int) * N_EDGES;
    int* gcur            = (int*)p;            p += sizeof(int) * NB;
    p = (char*)(((size_t)p + 15) & ~(size_t)15);
    unsigned* pairs      = (unsigned*)p;       p += sizeof(unsigned) * (size_t)NB * CAP;

    hipMemsetAsync(gcur, 0, sizeof(int) * NB, stream);
    k_bin<<<(N_EDGES + CHUNK - 1) / CHUNK, BIN_T, 0, stream>>>(row, col, gcur, pairs);
    k_fill2<<<NB, FILL_T, 0, stream>>>(pairs, gcur, offsets, dinv, src);
    k_xb<<<2048, 256, 0, stream>>>(x, dinv, xb);

    {
        const long long threads = (long long)N_NODES * 64;
        k_agg64<<<(int)((threads + 255) / 256), 256, 0, stream>>>(offsets, src, xb, aggb);
    }

    k_gemm<<<XW_NBLK, XW_T, 0, stream>>>(aggb, W1, dinv, b1, W2, z);

    k_out<<<(N_NODES + 255) / 256, 256, 0, stream>>>(offsets, src, z, dinv, b2, out, N_NODES);
}

// Round 10
// 122.102 us; speedup vs baseline: 12.9438x; 1.0820x over previous
//
#include <hip/hip_runtime.h>
#include <math.h>

#define N_NODES 100000
#define N_EDGES 1600000
#define D_IN 64
#define D_HID 128

#define BKT_SHIFT 9
#define BKT_NODES 512
#define NB ((N_NODES + BKT_NODES - 1) / BKT_NODES)  // 196
#define CAP 16384                                    // per-bucket capacity (mean ~8163)
#define CHUNK 8192
#define BIN_T 1024
#define FILL_T 1024

#define XW_T 256
#define XW_NODES 128
#define XW_NBLK ((N_NODES + XW_NODES - 1) / XW_NODES)  // 782

// packed edge: bits 0..16 = row (src node), bits 17..25 = dst & 511
#define PACK(row, col) (((unsigned)((col) & (BKT_NODES - 1)) << 17) | (unsigned)(row))
#define P_ROW(u) ((int)((u) & 0x1FFFFu))
#define P_DST(u) ((int)(((u) >> 17) & 0x1FFu))

static __device__ __forceinline__ unsigned short f2bf(float f) {
    unsigned int u = __float_as_uint(f);
    u += 0x7FFFu + ((u >> 16) & 1u);  // round-to-nearest-even
    return (unsigned short)(u >> 16);
}

// ---------------- phase 1: LDS counting-sort edges into 196 col-buckets ------

__global__ __launch_bounds__(BIN_T) void k_bin(const int* __restrict__ row,
                                               const int* __restrict__ col,
                                               int* __restrict__ gcur,
                                               unsigned* __restrict__ pairs) {
    __shared__ int bcnt[NB];
    __shared__ int boff[NB];
    __shared__ int gbase[NB];
    __shared__ int sc[256];
    __shared__ unsigned stage[CHUNK];          // 32 KB
    __shared__ unsigned char bkt_of[CHUNK];    // 8 KB
    const int t = threadIdx.x;
    const int e0 = blockIdx.x * CHUNK;
    const int nE = min(CHUNK, N_EDGES - e0);

    for (int i = t; i < NB; i += BIN_T) bcnt[i] = 0;
    __syncthreads();

    int myb[8], myrank[8], myr[8];
#pragma unroll
    for (int k = 0; k < 8; ++k) {
        const int i = t + k * BIN_T;
        if (i < nE) {
            myr[k] = row[e0 + i];
            const int c = col[e0 + i];
            myb[k] = c >> BKT_SHIFT;
            myrank[k] = atomicAdd(&bcnt[myb[k]], 1);
            myr[k] = PACK(myr[k], c);
        }
    }
    __syncthreads();

    if (t < 256) sc[t] = (t < NB) ? bcnt[t] : 0;
    __syncthreads();
    for (int off = 1; off < 256; off <<= 1) {
        int v = 0;
        if (t < 256 && t >= off) v = sc[t - off];
        __syncthreads();
        if (t < 256) sc[t] += v;
        __syncthreads();
    }
    if (t < NB) {
        boff[t] = sc[t] - bcnt[t];
        if (bcnt[t] > 0) gbase[t] = atomicAdd(&gcur[t], bcnt[t]);
    }
    __syncthreads();

    // stage into bucket-sorted order in LDS; record bucket per slot inline
#pragma unroll
    for (int k = 0; k < 8; ++k) {
        const int i = t + k * BIN_T;
        if (i < nE) {
            const int pos = boff[myb[k]] + myrank[k];
            stage[pos] = (unsigned)myr[k];
            bkt_of[pos] = (unsigned char)myb[k];
        }
    }
    __syncthreads();

    for (int s = t; s < nE; s += BIN_T) {
        const int b = bkt_of[s];
        pairs[(size_t)b * CAP + gbase[b] + (s - boff[b])] = stage[s];
    }
}

// ---------------- phase 2: per-bucket hist + scan + dense fill ----------------

__global__ __launch_bounds__(FILL_T) void k_fill2(const unsigned* __restrict__ pairs,
                                                  const int* __restrict__ gcur,
                                                  int* __restrict__ offsets,
                                                  float* __restrict__ dinv,
                                                  int* __restrict__ src) {
    __shared__ unsigned stage[CAP];      // 64 KB
    __shared__ int ncnt[BKT_NODES];
    __shared__ int ncur[BKT_NODES];
    __shared__ int sc[BKT_NODES];
    __shared__ int scb[256];
    const int b = blockIdx.x, t = threadIdx.x;
    const int base = b << BKT_SHIFT;
    const int nNodes = min(BKT_NODES, N_NODES - base);

    // redundant scan of the 196 bucket counts -> this block's global base
    if (t < 256) scb[t] = (t < NB) ? gcur[t] : 0;
    __syncthreads();
    for (int off = 1; off < 256; off <<= 1) {
        int v = 0;
        if (t < 256 && t >= off) v = scb[t - off];
        __syncthreads();
        if (t < 256) scb[t] += v;
        __syncthreads();
    }
    const int nE = gcur[b];
    const int gb = scb[b] - nE;  // exclusive prefix
    if (b == 0 && t == 0) offsets[N_NODES] = scb[NB - 1];

    const unsigned* bp = pairs + (size_t)b * CAP;
    for (int i = t; i < nE; i += FILL_T) stage[i] = bp[i];
    for (int i = t; i < BKT_NODES; i += FILL_T) ncnt[i] = 0;
    __syncthreads();

    for (int i = t; i < nE; i += FILL_T) atomicAdd(&ncnt[P_DST(stage[i])], 1);
    __syncthreads();

    const int c = (t < BKT_NODES) ? ncnt[t] : 0;
    if (t < BKT_NODES) sc[t] = c;
    __syncthreads();
    for (int off = 1; off < BKT_NODES; off <<= 1) {
        int u = 0;
        if (t < BKT_NODES && t >= off) u = sc[t - off];
        __syncthreads();
        if (t < BKT_NODES) sc[t] += u;
        __syncthreads();
    }
    if (t < BKT_NODES) {
        const int o = gb + sc[t] - c;  // exclusive
        if (t < nNodes) {
            offsets[base + t] = o;
            dinv[base + t] = rsqrtf((float)c + 1.0f);
        }
        ncur[t] = o;
    }
    __syncthreads();

    for (int i = t; i < nE; i += FILL_T) {
        const unsigned u = stage[i];
        const int pos = atomicAdd(&ncur[P_DST(u)], 1);
        src[pos] = P_ROW(u);
    }
}

// ---------------- xb = bf16(dinv * |x|), streaming elementwise ----------------

__global__ void k_xb(const float* __restrict__ x, const float* __restrict__ dinv,
                     unsigned short* __restrict__ xb) {
    const int total = N_NODES * (D_IN / 4);
    for (int i = blockIdx.x * blockDim.x + threadIdx.x; i < total;
         i += gridDim.x * blockDim.x) {
        const int n = i >> 4;
        const int q = i & 15;
        const float di = dinv[n];
        const float4 v = ((const float4*)(x + (size_t)n * D_IN))[q];
        ushort4 o4;
        o4.x = f2bf(di * fabsf(v.x));
        o4.y = f2bf(di * fabsf(v.y));
        o4.z = f2bf(di * fabsf(v.z));
        o4.w = f2bf(di * fabsf(v.w));
        *(ushort4*)(xb + (size_t)n * D_IN + q * 4) = o4;
    }
}

// ---------------- aggregate in input space: aggb = bf16(xb[node] + sum xb[src]) --
// 8 nodes per wave: lane = slot(3b) | dim-chunk(3b). No cross-lane reduction.

#define ACC8(v)                                                 \
    do {                                                        \
        a0 += __uint_as_float((v).x << 16);                     \
        a1 += __uint_as_float((v).x & 0xFFFF0000u);             \
        a2 += __uint_as_float((v).y << 16);                     \
        a3 += __uint_as_float((v).y & 0xFFFF0000u);             \
        a4 += __uint_as_float((v).z << 16);                     \
        a5 += __uint_as_float((v).z & 0xFFFF0000u);             \
        a6 += __uint_as_float((v).w << 16);                     \
        a7 += __uint_as_float((v).w & 0xFFFF0000u);             \
    } while (0)

__global__ void k_agg64(const int* __restrict__ offsets, const int* __restrict__ src,
                        const unsigned short* __restrict__ xb,
                        unsigned short* __restrict__ aggb) {
    const int t = blockIdx.x * blockDim.x + threadIdx.x;
    const int lane = t & 63;
    const int slot = lane >> 3;              // node slot 0..7
    const int dc = lane & 7;                 // dim chunk: dims 8*dc .. 8*dc+7
    const int node = (t >> 6) * 8 + slot;    // 8 nodes per wave
    if (node >= N_NODES) return;

    float a0 = 0, a1 = 0, a2 = 0, a3 = 0, a4 = 0, a5 = 0, a6 = 0, a7 = 0;

    {   // self-loop term (all lanes active, coalesced 1 KB per wave)
        const uint4 v = ((const uint4*)(xb + (size_t)node * D_IN))[dc];
        ACC8(v);
    }

    const int s0 = offsets[node], s1 = offsets[node + 1];
    int j = s0;
    for (; j + 1 < s1; j += 2) {  // 2 gathers in flight per 8-lane group (16/wave)
        const int r0 = src[j];
        const int r1 = src[j + 1];
        const uint4 v0 = ((const uint4*)(xb + (size_t)r0 * D_IN))[dc];
        const uint4 v1 = ((const uint4*)(xb + (size_t)r1 * D_IN))[dc];
        ACC8(v0);
        ACC8(v1);
    }
    if (j < s1) {
        const int r = src[j];
        const uint4 v = ((const uint4*)(xb + (size_t)r * D_IN))[dc];
        ACC8(v);
    }

    // pack this lane's 8 dims and store (wave writes 1 KB contiguous)
    uint4 w;
    w.x = (unsigned)f2bf(a0) | ((unsigned)f2bf(a1) << 16);
    w.y = (unsigned)f2bf(a2) | ((unsigned)f2bf(a3) << 16);
    w.z = (unsigned)f2bf(a4) | ((unsigned)f2bf(a5) << 16);
    w.w = (unsigned)f2bf(a6) | ((unsigned)f2bf(a7) << 16);
    *(uint4*)(aggb + (size_t)node * D_IN + dc * 8) = w;
}

// ---------------- fused GEMM: g = aggb @ W1; h=relu(di*g+b1); z=di*(h.W2) ----

__global__ __launch_bounds__(XW_T) void k_gemm(const unsigned short* __restrict__ aggb,
                                               const float* __restrict__ W1,
                                               const float* __restrict__ dinv,
                                               const float* __restrict__ b1,
                                               const float* __restrict__ W2,
                                               float* __restrict__ z) {
    __shared__ float ws[D_IN * D_HID];     // [k][dim]  32 KB
    __shared__ float xs[D_IN * XW_NODES];  // [k][node] 32 KB
    const int t = threadIdx.x;
    const int n0 = blockIdx.x * XW_NODES;

    {
        const float4* W4 = (const float4*)W1;
        float4* ws4 = (float4*)ws;
        for (int i = t; i < D_IN * D_HID / 4; i += XW_T) ws4[i] = W4[i];
    }
    {
        const int nl = t >> 1;
        const int h = t & 1;
        const int n = n0 + nl;
        if (n < N_NODES) {
            const uint4* xr = (const uint4*)(aggb + (size_t)n * D_IN + h * 32);
#pragma unroll
            for (int q = 0; q < 4; ++q) {
                const uint4 v = xr[q];
                const int k = h * 32 + q * 8;
                xs[(k + 0) * XW_NODES + nl] = __uint_as_float(v.x << 16);
                xs[(k + 1) * XW_NODES + nl] = __uint_as_float(v.x & 0xFFFF0000u);
                xs[(k + 2) * XW_NODES + nl] = __uint_as_float(v.y << 16);
                xs[(k + 3) * XW_NODES + nl] = __uint_as_float(v.y & 0xFFFF0000u);
                xs[(k + 4) * XW_NODES + nl] = __uint_as_float(v.z << 16);
                xs[(k + 5) * XW_NODES + nl] = __uint_as_float(v.z & 0xFFFF0000u);
                xs[(k + 6) * XW_NODES + nl] = __uint_as_float(v.w << 16);
                xs[(k + 7) * XW_NODES + nl] = __uint_as_float(v.w & 0xFFFF0000u);
            }
        } else {
#pragma unroll
            for (int q = 0; q < 8; ++q) {
                const int k = h * 32 + q * 4;
                xs[(k + 0) * XW_NODES + nl] = 0.0f;
                xs[(k + 1) * XW_NODES + nl] = 0.0f;
                xs[(k + 2) * XW_NODES + nl] = 0.0f;
                xs[(k + 3) * XW_NODES + nl] = 0.0f;
            }
        }
    }
    __syncthreads();

    const int tx = t & 15;
    const int ty = t >> 4;

    float acc0[8][4];
    float acc1[8][4];
#pragma unroll
    for (int i = 0; i < 8; ++i)
#pragma unroll
        for (int j = 0; j < 4; ++j) { acc0[i][j] = 0.0f; acc1[i][j] = 0.0f; }

    const float4* xs4 = (const float4*)xs;
    const float4* ws4 = (const float4*)ws;
#pragma unroll 4
    for (int k = 0; k < D_IN; ++k) {
        const float4 xa = xs4[k * 32 + ty * 2];
        const float4 xb_ = xs4[k * 32 + ty * 2 + 1];
        const float4 wa = ws4[k * 32 + tx];
        const float4 wb = ws4[k * 32 + 16 + tx];
        const float xn[8] = {xa.x, xa.y, xa.z, xa.w, xb_.x, xb_.y, xb_.z, xb_.w};
#pragma unroll
        for (int i = 0; i < 8; ++i) {
            acc0[i][0] = fmaf(xn[i], wa.x, acc0[i][0]);
            acc0[i][1] = fmaf(xn[i], wa.y, acc0[i][1]);
            acc0[i][2] = fmaf(xn[i], wa.z, acc0[i][2]);
            acc0[i][3] = fmaf(xn[i], wa.w, acc0[i][3]);
            acc1[i][0] = fmaf(xn[i], wb.x, acc1[i][0]);
            acc1[i][1] = fmaf(xn[i], wb.y, acc1[i][1]);
            acc1[i][2] = fmaf(xn[i], wb.z, acc1[i][2]);
            acc1[i][3] = fmaf(xn[i], wb.w, acc1[i][3]);
        }
    }

    // epilogue: h = relu(di*g + b1); partial = h . W2; butterfly over tx lanes
    const float4 b1a = ((const float4*)(b1 + 4 * tx))[0];
    const float4 b1b = ((const float4*)(b1 + 64 + 4 * tx))[0];
    const float4 w2a = ((const float4*)(W2 + 4 * tx))[0];
    const float4 w2b = ((const float4*)(W2 + 64 + 4 * tx))[0];
#pragma unroll
    for (int i = 0; i < 8; ++i) {
        const int n = n0 + ty * 8 + i;
        if (n >= N_NODES) continue;
        const float di = dinv[n];
        float h, sv;
        h = fmaxf(fmaf(di, acc0[i][0], b1a.x), 0.0f); sv = h * w2a.x;
        h = fmaxf(fmaf(di, acc0[i][1], b1a.y), 0.0f); sv = fmaf(h, w2a.y, sv);
        h = fmaxf(fmaf(di, acc0[i][2], b1a.z), 0.0f); sv = fmaf(h, w2a.z, sv);
        h = fmaxf(fmaf(di, acc0[i][3], b1a.w), 0.0f); sv = fmaf(h, w2a.w, sv);
        h = fmaxf(fmaf(di, acc1[i][0], b1b.x), 0.0f); sv = fmaf(h, w2b.x, sv);
        h = fmaxf(fmaf(di, acc1[i][1], b1b.y), 0.0f); sv = fmaf(h, w2b.y, sv);
        h = fmaxf(fmaf(di, acc1[i][2], b1b.z), 0.0f); sv = fmaf(h, w2b.z, sv);
        h = fmaxf(fmaf(di, acc1[i][3], b1b.w), 0.0f); sv = fmaf(h, w2b.w, sv);
#pragma unroll
        for (int m = 1; m <= 8; m <<= 1) sv += __shfl_xor(sv, m, 64);
        if (tx == 0) z[n] = di * sv;
    }
}

// ---------------- layer 2 aggregate + final ----------------

__global__ void k_out(const int* __restrict__ offsets, const int* __restrict__ src,
                      const float* __restrict__ z, const float* __restrict__ dinv,
                      const float* __restrict__ b2, float* __restrict__ out, int n) {
    const int i = blockIdx.x * blockDim.x + threadIdx.x;
    if (i >= n) return;
    float s = z[i];  // self-loop
    const int s0 = offsets[i], s1 = offsets[i + 1];
    int j = s0;
    for (; j + 3 < s1; j += 4)
        s += z[src[j]] + z[src[j + 1]] + z[src[j + 2]] + z[src[j + 3]];
    for (; j < s1; ++j) s += z[src[j]];
    float v = fmaf(dinv[i], s, b2[0]);
    v = fmaxf(v, 0.0f);
    out[i] = 1.0f / (1.0f + expf(-v));
}

extern "C" void kernel_launch(void* const* d_in, const int* in_sizes, int n_in,
                              void* d_out, int out_size, void* d_ws, size_t ws_size,
                              hipStream_t stream) {
    const float* x  = (const float*)d_in[0];
    const int* ei   = (const int*)d_in[1];
    const float* W1 = (const float*)d_in[2];
    const float* b1 = (const float*)d_in[3];
    const float* W2 = (const float*)d_in[4];
    const float* b2 = (const float*)d_in[5];
    float* out = (float*)d_out;

    const int* row = ei;
    const int* col = ei + N_EDGES;

    // workspace layout
    char* p = (char*)d_ws;
    float* dinv          = (float*)p;          p += sizeof(float) * N_NODES;
    unsigned short* xb   = (unsigned short*)p; p += sizeof(unsigned short) * (size_t)N_NODES * D_IN;
    unsigned short* aggb = (unsigned short*)p; p += sizeof(unsigned short) * (size_t)N_NODES * D_IN;
    float* z             = (float*)p;          p += sizeof(float) * N_NODES;
    int* offsets         = (int*)p;            p += sizeof(int) * (N_NODES + 1);
    int* src             = (int*)p;            p += sizeof(int) * N_EDGES;
    int* gcur            = (int*)p;            p += sizeof(int) * NB;
    p = (char*)(((size_t)p + 15) & ~(size_t)15);
    unsigned* pairs      = (unsigned*)p;       p += sizeof(unsigned) * (size_t)NB * CAP;

    hipMemsetAsync(gcur, 0, sizeof(int) * NB, stream);
    k_bin<<<(N_EDGES + CHUNK - 1) / CHUNK, BIN_T, 0, stream>>>(row, col, gcur, pairs);
    k_fill2<<<NB, FILL_T, 0, stream>>>(pairs, gcur, offsets, dinv, src);
    k_xb<<<2048, 256, 0, stream>>>(x, dinv, xb);

    {
        const long long threads = ((long long)N_NODES + 7) / 8 * 64;
        k_agg64<<<(int)((threads + 255) / 256), 256, 0, stream>>>(offsets, src, xb, aggb);
    }

    k_gemm<<<XW_NBLK, XW_T, 0, stream>>>(aggb, W1, dinv, b1, W2, z);

    k_out<<<(N_NODES + 255) / 256, 256, 0, stream>>>(offsets, src, z, dinv, b2, out, N_NODES);
}

// Round 11
// 116.957 us; speedup vs baseline: 13.5132x; 1.0440x over previous
//
#include <hip/hip_runtime.h>
#include <math.h>

#define N_NODES 100000
#define N_EDGES 1600000
#define D_IN 64
#define D_HID 128

#define BKT_SHIFT 9
#define BKT_NODES 512
#define NB ((N_NODES + BKT_NODES - 1) / BKT_NODES)  // 196
#define CAP 16384                                    // per-bucket capacity (mean ~8163)
#define CHUNK 8192
#define BIN_T 1024
#define FILL_T 1024

#define XW_T 256
#define XW_NODES 128
#define XW_NBLK ((N_NODES + XW_NODES - 1) / XW_NODES)  // 782

// packed edge: bits 0..16 = row (src node), bits 17..25 = dst & 511
#define PACK(row, col) (((unsigned)((col) & (BKT_NODES - 1)) << 17) | (unsigned)(row))
#define P_ROW(u) ((int)((u) & 0x1FFFFu))
#define P_DST(u) ((int)(((u) >> 17) & 0x1FFu))

static __device__ __forceinline__ unsigned short f2bf(float f) {
    unsigned int u = __float_as_uint(f);
    u += 0x7FFFu + ((u >> 16) & 1u);  // round-to-nearest-even
    return (unsigned short)(u >> 16);
}

// ---------------- phase 1: LDS counting-sort edges into 196 col-buckets ------

__global__ __launch_bounds__(BIN_T) void k_bin(const int* __restrict__ row,
                                               const int* __restrict__ col,
                                               int* __restrict__ gcur,
                                               unsigned* __restrict__ pairs) {
    __shared__ int bcnt[NB];
    __shared__ int boff[NB];
    __shared__ int gbase[NB];
    __shared__ int sc[256];
    __shared__ unsigned stage[CHUNK];          // 32 KB
    __shared__ unsigned char bkt_of[CHUNK];    // 8 KB
    const int t = threadIdx.x;
    const int e0 = blockIdx.x * CHUNK;
    const int nE = min(CHUNK, N_EDGES - e0);

    for (int i = t; i < NB; i += BIN_T) bcnt[i] = 0;
    __syncthreads();

    int myb[8], myrank[8], myr[8];
#pragma unroll
    for (int k = 0; k < 8; ++k) {
        const int i = t + k * BIN_T;
        if (i < nE) {
            myr[k] = row[e0 + i];
            const int c = col[e0 + i];
            myb[k] = c >> BKT_SHIFT;
            myrank[k] = atomicAdd(&bcnt[myb[k]], 1);
            myr[k] = PACK(myr[k], c);
        }
    }
    __syncthreads();

    if (t < 256) sc[t] = (t < NB) ? bcnt[t] : 0;
    __syncthreads();
    for (int off = 1; off < 256; off <<= 1) {
        int v = 0;
        if (t < 256 && t >= off) v = sc[t - off];
        __syncthreads();
        if (t < 256) sc[t] += v;
        __syncthreads();
    }
    if (t < NB) {
        boff[t] = sc[t] - bcnt[t];
        if (bcnt[t] > 0) gbase[t] = atomicAdd(&gcur[t], bcnt[t]);
    }
    __syncthreads();

    // stage into bucket-sorted order in LDS; record bucket per slot inline
#pragma unroll
    for (int k = 0; k < 8; ++k) {
        const int i = t + k * BIN_T;
        if (i < nE) {
            const int pos = boff[myb[k]] + myrank[k];
            stage[pos] = (unsigned)myr[k];
            bkt_of[pos] = (unsigned char)myb[k];
        }
    }
    __syncthreads();

    for (int s = t; s < nE; s += BIN_T) {
        const int b = bkt_of[s];
        pairs[(size_t)b * CAP + gbase[b] + (s - boff[b])] = stage[s];
    }
}

// ---------------- phase 2: per-bucket hist + scan + dense fill + xb ----------

__global__ __launch_bounds__(FILL_T) void k_fill2(const unsigned* __restrict__ pairs,
                                                  const int* __restrict__ gcur,
                                                  const float* __restrict__ x,
                                                  int* __restrict__ offsets,
                                                  float* __restrict__ dinv,
                                                  int* __restrict__ src,
                                                  unsigned short* __restrict__ xb) {
    __shared__ unsigned stage[CAP];      // 64 KB
    __shared__ int ncnt[BKT_NODES];
    __shared__ int ncur[BKT_NODES];
    __shared__ int sc[BKT_NODES];
    __shared__ int scb[256];
    const int b = blockIdx.x, t = threadIdx.x;
    const int base = b << BKT_SHIFT;
    const int nNodes = min(BKT_NODES, N_NODES - base);

    // redundant scan of the 196 bucket counts -> this block's global base
    if (t < 256) scb[t] = (t < NB) ? gcur[t] : 0;
    __syncthreads();
    for (int off = 1; off < 256; off <<= 1) {
        int v = 0;
        if (t < 256 && t >= off) v = scb[t - off];
        __syncthreads();
        if (t < 256) scb[t] += v;
        __syncthreads();
    }
    const int nE = gcur[b];
    const int gb = scb[b] - nE;  // exclusive prefix
    if (b == 0 && t == 0) offsets[N_NODES] = scb[NB - 1];

    const unsigned* bp = pairs + (size_t)b * CAP;
    for (int i = t; i < nE; i += FILL_T) stage[i] = bp[i];
    for (int i = t; i < BKT_NODES; i += FILL_T) ncnt[i] = 0;
    __syncthreads();

    for (int i = t; i < nE; i += FILL_T) atomicAdd(&ncnt[P_DST(stage[i])], 1);
    __syncthreads();

    const int c = (t < BKT_NODES) ? ncnt[t] : 0;
    if (t < BKT_NODES) sc[t] = c;
    __syncthreads();
    for (int off = 1; off < BKT_NODES; off <<= 1) {
        int u = 0;
        if (t < BKT_NODES && t >= off) u = sc[t - off];
        __syncthreads();
        if (t < BKT_NODES) sc[t] += u;
        __syncthreads();
    }
    if (t < BKT_NODES) {
        const int o = gb + sc[t] - c;  // exclusive
        if (t < nNodes) {
            offsets[base + t] = o;
            dinv[base + t] = rsqrtf((float)c + 1.0f);
        }
        ncur[t] = o;
    }
    __syncthreads();

    for (int i = t; i < nE; i += FILL_T) {
        const unsigned u = stage[i];
        const int pos = atomicAdd(&ncur[P_DST(u)], 1);
        src[pos] = P_ROW(u);
    }

    // xb = bf16(dinv * |x|) for this bucket's nodes (ncnt still holds degrees)
    for (int i = t; i < nNodes * (D_IN / 4); i += FILL_T) {
        const int nl = i >> 4;           // local node
        const int q = i & 15;            // float4 index within row
        const float di = rsqrtf((float)ncnt[nl] + 1.0f);
        const float4 v = ((const float4*)(x + (size_t)(base + nl) * D_IN))[q];
        ushort4 o4;
        o4.x = f2bf(di * fabsf(v.x));
        o4.y = f2bf(di * fabsf(v.y));
        o4.z = f2bf(di * fabsf(v.z));
        o4.w = f2bf(di * fabsf(v.w));
        *(ushort4*)(xb + (size_t)(base + nl) * D_IN + q * 4) = o4;
    }
}

// ---------------- aggregate in input space: aggb = bf16(xb[node] + sum xb[src]) --
// 8 nodes per wave: lane = slot(3b) | dim-chunk(3b). No cross-lane reduction.

#define ACC8(v)                                                 \
    do {                                                        \
        a0 += __uint_as_float((v).x << 16);                     \
        a1 += __uint_as_float((v).x & 0xFFFF0000u);             \
        a2 += __uint_as_float((v).y << 16);                     \
        a3 += __uint_as_float((v).y & 0xFFFF0000u);             \
        a4 += __uint_as_float((v).z << 16);                     \
        a5 += __uint_as_float((v).z & 0xFFFF0000u);             \
        a6 += __uint_as_float((v).w << 16);                     \
        a7 += __uint_as_float((v).w & 0xFFFF0000u);             \
    } while (0)

__global__ void k_agg64(const int* __restrict__ offsets, const int* __restrict__ src,
                        const unsigned short* __restrict__ xb,
                        unsigned short* __restrict__ aggb) {
    const int t = blockIdx.x * blockDim.x + threadIdx.x;
    const int lane = t & 63;
    const int slot = lane >> 3;              // node slot 0..7
    const int dc = lane & 7;                 // dim chunk: dims 8*dc .. 8*dc+7
    const int node = (t >> 6) * 8 + slot;    // 8 nodes per wave
    if (node >= N_NODES) return;

    float a0 = 0, a1 = 0, a2 = 0, a3 = 0, a4 = 0, a5 = 0, a6 = 0, a7 = 0;

    {   // self-loop term (all lanes active, coalesced 1 KB per wave)
        const uint4 v = ((const uint4*)(xb + (size_t)node * D_IN))[dc];
        ACC8(v);
    }

    const int s0 = offsets[node], s1 = offsets[node + 1];
    int j = s0;
    for (; j + 3 < s1; j += 4) {  // 4 gathers in flight per 8-lane group (32/wave)
        const int r0 = src[j];
        const int r1 = src[j + 1];
        const int r2 = src[j + 2];
        const int r3 = src[j + 3];
        const uint4 v0 = ((const uint4*)(xb + (size_t)r0 * D_IN))[dc];
        const uint4 v1 = ((const uint4*)(xb + (size_t)r1 * D_IN))[dc];
        const uint4 v2 = ((const uint4*)(xb + (size_t)r2 * D_IN))[dc];
        const uint4 v3 = ((const uint4*)(xb + (size_t)r3 * D_IN))[dc];
        ACC8(v0);
        ACC8(v1);
        ACC8(v2);
        ACC8(v3);
    }
    for (; j < s1; ++j) {
        const int r = src[j];
        const uint4 v = ((const uint4*)(xb + (size_t)r * D_IN))[dc];
        ACC8(v);
    }

    // pack this lane's 8 dims and store (wave writes 1 KB contiguous)
    uint4 w;
    w.x = (unsigned)f2bf(a0) | ((unsigned)f2bf(a1) << 16);
    w.y = (unsigned)f2bf(a2) | ((unsigned)f2bf(a3) << 16);
    w.z = (unsigned)f2bf(a4) | ((unsigned)f2bf(a5) << 16);
    w.w = (unsigned)f2bf(a6) | ((unsigned)f2bf(a7) << 16);
    *(uint4*)(aggb + (size_t)node * D_IN + dc * 8) = w;
}

// ---------------- fused GEMM: g = aggb @ W1; h=relu(di*g+b1); z=di*(h.W2) ----

__global__ __launch_bounds__(XW_T) void k_gemm(const unsigned short* __restrict__ aggb,
                                               const float* __restrict__ W1,
                                               const float* __restrict__ dinv,
                                               const float* __restrict__ b1,
                                               const float* __restrict__ W2,
                                               float* __restrict__ z) {
    __shared__ float ws[D_IN * D_HID];     // [k][dim]  32 KB
    __shared__ float xs[D_IN * XW_NODES];  // [k][node] 32 KB
    const int t = threadIdx.x;
    const int n0 = blockIdx.x * XW_NODES;

    {
        const float4* W4 = (const float4*)W1;
        float4* ws4 = (float4*)ws;
        for (int i = t; i < D_IN * D_HID / 4; i += XW_T) ws4[i] = W4[i];
    }
    {
        const int nl = t >> 1;
        const int h = t & 1;
        const int n = n0 + nl;
        if (n < N_NODES) {
            const uint4* xr = (const uint4*)(aggb + (size_t)n * D_IN + h * 32);
#pragma unroll
            for (int q = 0; q < 4; ++q) {
                const uint4 v = xr[q];
                const int k = h * 32 + q * 8;
                xs[(k + 0) * XW_NODES + nl] = __uint_as_float(v.x << 16);
                xs[(k + 1) * XW_NODES + nl] = __uint_as_float(v.x & 0xFFFF0000u);
                xs[(k + 2) * XW_NODES + nl] = __uint_as_float(v.y << 16);
                xs[(k + 3) * XW_NODES + nl] = __uint_as_float(v.y & 0xFFFF0000u);
                xs[(k + 4) * XW_NODES + nl] = __uint_as_float(v.z << 16);
                xs[(k + 5) * XW_NODES + nl] = __uint_as_float(v.z & 0xFFFF0000u);
                xs[(k + 6) * XW_NODES + nl] = __uint_as_float(v.w << 16);
                xs[(k + 7) * XW_NODES + nl] = __uint_as_float(v.w & 0xFFFF0000u);
            }
        } else {
#pragma unroll
            for (int q = 0; q < 8; ++q) {
                const int k = h * 32 + q * 4;
                xs[(k + 0) * XW_NODES + nl] = 0.0f;
                xs[(k + 1) * XW_NODES + nl] = 0.0f;
                xs[(k + 2) * XW_NODES + nl] = 0.0f;
                xs[(k + 3) * XW_NODES + nl] = 0.0f;
            }
        }
    }
    __syncthreads();

    const int tx = t & 15;
    const int ty = t >> 4;

    float acc0[8][4];
    float acc1[8][4];
#pragma unroll
    for (int i = 0; i < 8; ++i)
#pragma unroll
        for (int j = 0; j < 4; ++j) { acc0[i][j] = 0.0f; acc1[i][j] = 0.0f; }

    const float4* xs4 = (const float4*)xs;
    const float4* ws4 = (const float4*)ws;
#pragma unroll 4
    for (int k = 0; k < D_IN; ++k) {
        const float4 xa = xs4[k * 32 + ty * 2];
        const float4 xb_ = xs4[k * 32 + ty * 2 + 1];
        const float4 wa = ws4[k * 32 + tx];
        const float4 wb = ws4[k * 32 + 16 + tx];
        const float xn[8] = {xa.x, xa.y, xa.z, xa.w, xb_.x, xb_.y, xb_.z, xb_.w};
#pragma unroll
        for (int i = 0; i < 8; ++i) {
            acc0[i][0] = fmaf(xn[i], wa.x, acc0[i][0]);
            acc0[i][1] = fmaf(xn[i], wa.y, acc0[i][1]);
            acc0[i][2] = fmaf(xn[i], wa.z, acc0[i][2]);
            acc0[i][3] = fmaf(xn[i], wa.w, acc0[i][3]);
            acc1[i][0] = fmaf(xn[i], wb.x, acc1[i][0]);
            acc1[i][1] = fmaf(xn[i], wb.y, acc1[i][1]);
            acc1[i][2] = fmaf(xn[i], wb.z, acc1[i][2]);
            acc1[i][3] = fmaf(xn[i], wb.w, acc1[i][3]);
        }
    }

    // epilogue: h = relu(di*g + b1); partial = h . W2; butterfly over tx lanes
    const float4 b1a = ((const float4*)(b1 + 4 * tx))[0];
    const float4 b1b = ((const float4*)(b1 + 64 + 4 * tx))[0];
    const float4 w2a = ((const float4*)(W2 + 4 * tx))[0];
    const float4 w2b = ((const float4*)(W2 + 64 + 4 * tx))[0];
#pragma unroll
    for (int i = 0; i < 8; ++i) {
        const int n = n0 + ty * 8 + i;
        if (n >= N_NODES) continue;
        const float di = dinv[n];
        float h, sv;
        h = fmaxf(fmaf(di, acc0[i][0], b1a.x), 0.0f); sv = h * w2a.x;
        h = fmaxf(fmaf(di, acc0[i][1], b1a.y), 0.0f); sv = fmaf(h, w2a.y, sv);
        h = fmaxf(fmaf(di, acc0[i][2], b1a.z), 0.0f); sv = fmaf(h, w2a.z, sv);
        h = fmaxf(fmaf(di, acc0[i][3], b1a.w), 0.0f); sv = fmaf(h, w2a.w, sv);
        h = fmaxf(fmaf(di, acc1[i][0], b1b.x), 0.0f); sv = fmaf(h, w2b.x, sv);
        h = fmaxf(fmaf(di, acc1[i][1], b1b.y), 0.0f); sv = fmaf(h, w2b.y, sv);
        h = fmaxf(fmaf(di, acc1[i][2], b1b.z), 0.0f); sv = fmaf(h, w2b.z, sv);
        h = fmaxf(fmaf(di, acc1[i][3], b1b.w), 0.0f); sv = fmaf(h, w2b.w, sv);
#pragma unroll
        for (int m = 1; m <= 8; m <<= 1) sv += __shfl_xor(sv, m, 64);
        if (tx == 0) z[n] = di * sv;
    }
}

// ---------------- layer 2 aggregate + final ----------------

__global__ void k_out(const int* __restrict__ offsets, const int* __restrict__ src,
                      const float* __restrict__ z, const float* __restrict__ dinv,
                      const float* __restrict__ b2, float* __restrict__ out, int n) {
    const int i = blockIdx.x * blockDim.x + threadIdx.x;
    if (i >= n) return;
    float s = z[i];  // self-loop
    const int s0 = offsets[i], s1 = offsets[i + 1];
    int j = s0;
    for (; j + 3 < s1; j += 4)
        s += z[src[j]] + z[src[j + 1]] + z[src[j + 2]] + z[src[j + 3]];
    for (; j < s1; ++j) s += z[src[j]];
    float v = fmaf(dinv[i], s, b2[0]);
    v = fmaxf(v, 0.0f);
    out[i] = 1.0f / (1.0f + expf(-v));
}

extern "C" void kernel_launch(void* const* d_in, const int* in_sizes, int n_in,
                              void* d_out, int out_size, void* d_ws, size_t ws_size,
                              hipStream_t stream) {
    const float* x  = (const float*)d_in[0];
    const int* ei   = (const int*)d_in[1];
    const float* W1 = (const float*)d_in[2];
    const float* b1 = (const float*)d_in[3];
    const float* W2 = (const float*)d_in[4];
    const float* b2 = (const float*)d_in[5];
    float* out = (float*)d_out;

    const int* row = ei;
    const int* col = ei + N_EDGES;

    // workspace layout
    char* p = (char*)d_ws;
    float* dinv          = (float*)p;          p += sizeof(float) * N_NODES;
    unsigned short* xb   = (unsigned short*)p; p += sizeof(unsigned short) * (size_t)N_NODES * D_IN;
    unsigned short* aggb = (unsigned short*)p; p += sizeof(unsigned short) * (size_t)N_NODES * D_IN;
    float* z             = (float*)p;          p += sizeof(float) * N_NODES;
    int* offsets         = (int*)p;            p += sizeof(int) * (N_NODES + 1);
    int* src             = (int*)p;            p += sizeof(int) * N_EDGES;
    int* gcur            = (int*)p;            p += sizeof(int) * NB;
    p = (char*)(((size_t)p + 15) & ~(size_t)15);
    unsigned* pairs      = (unsigned*)p;       p += sizeof(unsigned) * (size_t)NB * CAP;

    hipMemsetAsync(gcur, 0, sizeof(int) * NB, stream);
    k_bin<<<(N_EDGES + CHUNK - 1) / CHUNK, BIN_T, 0, stream>>>(row, col, gcur, pairs);
    k_fill2<<<NB, FILL_T, 0, stream>>>(pairs, gcur, x, offsets, dinv, src, xb);

    {
        const long long threads = ((long long)N_NODES + 7) / 8 * 64;
        k_agg64<<<(int)((threads + 255) / 256), 256, 0, stream>>>(offsets, src, xb, aggb);
    }

    k_gemm<<<XW_NBLK, XW_T, 0, stream>>>(aggb, W1, dinv, b1, W2, z);

    k_out<<<(N_NODES + 255) / 256, 256, 0, stream>>>(offsets, src, z, dinv, b2, out, N_NODES);
}